// Round 1
// baseline (1142.085 us; speedup 1.0000x reference)
//
#include <hip/hip_runtime.h>
#include <hip/hip_bf16.h>
#include <stdint.h>

#define N_NODES 20000
#define DIM     768
#define NREL    8
#define NEDGE   320000
#define NSEG    (N_NODES * NREL)   // 160000
#define GKA     6144   // NREL*DIM  (aggregated part of K)
#define GK      6912   // GKA + DIM (full K incl. root)
#define NT_TILES (GK / 64)         // 108 K-tiles of 64
#define NPW     2      // nodes per wave in aggregate

typedef short short8 __attribute__((ext_vector_type(8)));
typedef float f32x4  __attribute__((ext_vector_type(4)));

__device__ __forceinline__ void async_load16(const void* g, void* l) {
  __builtin_amdgcn_global_load_lds((const __attribute__((address_space(1))) void*)g,
                                   (__attribute__((address_space(3))) void*)l,
                                   16, 0, 0);
}

__device__ __forceinline__ int imin(int a, int b) { return a < b ? a : b; }

__device__ __forceinline__ float bf_lo(uint32_t v) {
  return __builtin_bit_cast(float, v << 16);
}
__device__ __forceinline__ float bf_hi(uint32_t v) {
  return __builtin_bit_cast(float, v & 0xffff0000u);
}
__device__ __forceinline__ uint32_t pack_bf16x2(float a, float b) {
  uint32_t lo = __builtin_bit_cast(unsigned short, __float2bfloat16(a));
  uint32_t hi = __builtin_bit_cast(unsigned short, __float2bfloat16(b));
  return lo | (hi << 16);
}

// ---------------------------------------------------------------- segment CSR build
__global__ void seg_count_kernel(const int* __restrict__ dst, const int* __restrict__ et,
                                 int* __restrict__ segcnt, int e_cnt) {
  int e = blockIdx.x * 256 + threadIdx.x;
  if (e < e_cnt) atomicAdd(&segcnt[dst[e] * NREL + et[e]], 1);
}

// hierarchical scan over NSEG bins: per-block exclusive scan + partials
__global__ void block_scan_kernel(const int* __restrict__ in, int* __restrict__ out,
                                  int* __restrict__ partials, int n) {
  __shared__ int wsum[16];
  const int t = threadIdx.x, lane = t & 63, wave = t >> 6;
  const int i = blockIdx.x * 1024 + t;
  int v = (i < n) ? in[i] : 0;
  int s = v;
#pragma unroll
  for (int off = 1; off < 64; off <<= 1) {
    int u = __shfl_up(s, off, 64);
    if (lane >= off) s += u;
  }
  if (lane == 63) wsum[wave] = s;
  __syncthreads();
  if (t < 16) {
    int w = wsum[t];
#pragma unroll
    for (int off = 1; off < 16; off <<= 1) {
      int u = __shfl_up(w, off, 64);
      if (t >= off) w += u;
    }
    wsum[t] = w;
  }
  __syncthreads();
  const int basew = (wave > 0) ? wsum[wave - 1] : 0;
  if (i < n) out[i] = basew + s - v;        // block-local exclusive
  if (t == 1023) partials[blockIdx.x] = wsum[15];
}

// single-wave scan of block partials (in place, exclusive)
__global__ void partial_scan_kernel(int* __restrict__ partials, int nb) {
  const int lane = threadIdx.x & 63;
  int carry = 0;
  for (int base = 0; base < nb; base += 64) {
    const int i = base + lane;
    int v = (i < nb) ? partials[i] : 0;
    int s = v;
#pragma unroll
    for (int off = 1; off < 64; off <<= 1) {
      int u = __shfl_up(s, off, 64);
      if (lane >= off) s += u;
    }
    if (i < nb) partials[i] = carry + s - v;
    carry += __shfl(s, 63, 64);
  }
}

__global__ void add_offsets_kernel(int* __restrict__ soffs, const int* __restrict__ partials,
                                   int* __restrict__ cursor, int n) {
  const int i = blockIdx.x * 1024 + threadIdx.x;   // blockDim must be 1024
  if (i < n) {
    const int v = soffs[i] + partials[blockIdx.x];
    soffs[i] = v;
    cursor[i] = v;
  }
  if (i == 0) soffs[n] = NEDGE;
}

__global__ void seg_scatter_kernel(const int* __restrict__ src, const int* __restrict__ dst,
                                   const int* __restrict__ et, int* __restrict__ cursor,
                                   int* __restrict__ es, int e_cnt) {
  int e = blockIdx.x * 256 + threadIdx.x;
  if (e < e_cnt) {
    const int seg = dst[e] * NREL + et[e];
    const int p = atomicAdd(&cursor[seg], 1);
    es[p] = src[e];
  }
}

// ---------------------------------------------------------------- fp32 -> bf16
__global__ void cvt_bf16_kernel(const float4* __restrict__ in, ushort4* __restrict__ out, int n4) {
  int i = blockIdx.x * 256 + threadIdx.x;
  if (i < n4) {
    float4 f = in[i];
    ushort4 r;
    r.x = __builtin_bit_cast(unsigned short, __float2bfloat16(f.x));
    r.y = __builtin_bit_cast(unsigned short, __float2bfloat16(f.y));
    r.z = __builtin_bit_cast(unsigned short, __float2bfloat16(f.z));
    r.w = __builtin_bit_cast(unsigned short, __float2bfloat16(f.w));
    out[i] = r;
  }
}

// ------------------------------------------------- weight transpose (f32 src [rows][DIM] -> bf16 dst [DIM][GK])
__global__ void transpose_w_kernel(const float* __restrict__ src, __hip_bfloat16* __restrict__ dst,
                                   int rows, int col_off) {
  __shared__ float tile[32][33];
  const int c0 = blockIdx.x * 32;
  const int r0 = blockIdx.y * 32;
  const int tx = threadIdx.x, ty = threadIdx.y;  // 32x8
  for (int i = ty; i < 32; i += 8) {
    int r = r0 + i, c = c0 + tx;
    tile[i][tx] = (r < rows) ? src[(size_t)r * DIM + c] : 0.f;
  }
  __syncthreads();
  for (int i = ty; i < 32; i += 8) {
    int c = c0 + i, r = r0 + tx;
    if (r < rows)
      dst[(size_t)c * GK + col_off + r] = __float2bfloat16(tile[tx][i]);
  }
}

// ---------------------------------------------------------------- aggregation
// Edges pre-sorted by (dst, rel): soffs[n*8+r] gives each (node,rel) segment.
// One wave owns a full 768-feature row: lane holds 12 bf16 (3x dwordx2 at
// byte offsets lane*8 + {0,512,1024}). Only 12 live accumulators (current
// segment). No relation switch, no er loads; cnt = segment length. Empty
// segments naturally write zeros. Edge loop 2-way unrolled (6 gathers in flight).
__global__ __launch_bounds__(256) void aggregate_kernel(
    const __hip_bfloat16* __restrict__ feat,  // [N_NODES][DIM] bf16
    const int* __restrict__ soffs, const int* __restrict__ es,
    __hip_bfloat16* __restrict__ Abuf,        // [caprows][GKA], chunk-local rows
    int node_base, int rows) {
  const int t = threadIdx.x;
  const int lane = t & 63;
  const int wave = t >> 6;
  const int boff = lane * 8;                  // byte offset within 512B third

  int nloc = (blockIdx.x * 4 + wave) * NPW;
  for (int it = 0; it < NPW; ++it, ++nloc) {
    if (nloc >= rows) return;
    const int n = node_base + nloc;
    char* Ab = (char*)(Abuf + (size_t)nloc * GKA);
#pragma unroll
    for (int r = 0; r < NREL; ++r) {
      const int beg = soffs[n * NREL + r], end = soffs[n * NREL + r + 1];
      float acc[12];
#pragma unroll
      for (int i = 0; i < 12; ++i) acc[i] = 0.f;
      int e = beg;
      for (; e + 2 <= end; e += 2) {
        const int s0 = es[e], s1 = es[e + 1];
        const char* p0 = (const char*)(feat + (size_t)s0 * DIM) + boff;
        const char* p1 = (const char*)(feat + (size_t)s1 * DIM) + boff;
        const uint2 a0 = *(const uint2*)(p0);
        const uint2 a1 = *(const uint2*)(p0 + 512);
        const uint2 a2 = *(const uint2*)(p0 + 1024);
        const uint2 b0 = *(const uint2*)(p1);
        const uint2 b1 = *(const uint2*)(p1 + 512);
        const uint2 b2 = *(const uint2*)(p1 + 1024);
        acc[0]  += bf_lo(a0.x); acc[1]  += bf_hi(a0.x);
        acc[2]  += bf_lo(a0.y); acc[3]  += bf_hi(a0.y);
        acc[4]  += bf_lo(a1.x); acc[5]  += bf_hi(a1.x);
        acc[6]  += bf_lo(a1.y); acc[7]  += bf_hi(a1.y);
        acc[8]  += bf_lo(a2.x); acc[9]  += bf_hi(a2.x);
        acc[10] += bf_lo(a2.y); acc[11] += bf_hi(a2.y);
        acc[0]  += bf_lo(b0.x); acc[1]  += bf_hi(b0.x);
        acc[2]  += bf_lo(b0.y); acc[3]  += bf_hi(b0.y);
        acc[4]  += bf_lo(b1.x); acc[5]  += bf_hi(b1.x);
        acc[6]  += bf_lo(b1.y); acc[7]  += bf_hi(b1.y);
        acc[8]  += bf_lo(b2.x); acc[9]  += bf_hi(b2.x);
        acc[10] += bf_lo(b2.y); acc[11] += bf_hi(b2.y);
      }
      if (e < end) {
        const int s0 = es[e];
        const char* p0 = (const char*)(feat + (size_t)s0 * DIM) + boff;
        const uint2 a0 = *(const uint2*)(p0);
        const uint2 a1 = *(const uint2*)(p0 + 512);
        const uint2 a2 = *(const uint2*)(p0 + 1024);
        acc[0]  += bf_lo(a0.x); acc[1]  += bf_hi(a0.x);
        acc[2]  += bf_lo(a0.y); acc[3]  += bf_hi(a0.y);
        acc[4]  += bf_lo(a1.x); acc[5]  += bf_hi(a1.x);
        acc[6]  += bf_lo(a1.y); acc[7]  += bf_hi(a1.y);
        acc[8]  += bf_lo(a2.x); acc[9]  += bf_hi(a2.x);
        acc[10] += bf_lo(a2.y); acc[11] += bf_hi(a2.y);
      }
      const float inv = 1.f / fmaxf((float)(end - beg), 1.f);
      uint2 o0, o1, o2;
      o0.x = pack_bf16x2(acc[0] * inv, acc[1] * inv);
      o0.y = pack_bf16x2(acc[2] * inv, acc[3] * inv);
      o1.x = pack_bf16x2(acc[4] * inv, acc[5] * inv);
      o1.y = pack_bf16x2(acc[6] * inv, acc[7] * inv);
      o2.x = pack_bf16x2(acc[8] * inv, acc[9] * inv);
      o2.y = pack_bf16x2(acc[10] * inv, acc[11] * inv);
      char* dst = Ab + r * (DIM * 2);
      *(uint2*)(dst + boff) = o0;
      *(uint2*)(dst + boff + 512) = o1;
      *(uint2*)(dst + boff + 1024) = o2;
    }
  }
}

// ---------------------------------------------------------------- GEMM (256^2, 8-wave, phase-interleaved)
// C[m,o] = sum_k Acat[m,k] * WT[o,k] (+bias).  Acat = [Amean (6144) | feat (768)].
// 256x256 tile, BK=64, 512 threads = 8 waves (2M x 4N); per-wave C = 128x64 as
// two row-halves x two col-halves (interleaved so phase (mh,nh) touches exactly
// one A-slot and one B-slot).  LDS: 2 buffers x {A[2][128][64], B[2][128][64]}
// bf16 = 128 KiB, linear layout + pre-swizzled global source (XOR granule ^ row&7,
// proven conflict-free).  Per K-tile: 4 phases {l0..l3}; stage schedule:
//   l0: A1,B1 of tile T+1 -> buf^1     (slots' prior readers ended at T-1)
//   l2: A0 of tile T+2   -> buf        (A0(T) last ds-read at l0)
//   l3: B0 of tile T+2   -> buf        (B0(T) last ds-read at l0)
// Counted waits: vmcnt(4) at l0, vmcnt(6) at l3 -- never 0 in the loop.
// Steady state after l3: exactly {A1,B1(T+1), A0,B0(T+2)} = 8 loads in flight.
// A/B fragments register-cached: 24 ds_read_b128 per tile per wave vs 64 MFMA.
// K accumulation order identical to previous kernel -> bit-identical output.
__global__ __launch_bounds__(512, 2) void gemm_kernel(
    const __hip_bfloat16* __restrict__ A,     // [rows][GKA] chunk-local
    const __hip_bfloat16* __restrict__ feat,  // [N_NODES][DIM] root operand
    const __hip_bfloat16* __restrict__ BT,    // [DIM][GK]
    const float* __restrict__ bias,           // [DIM]
    __hip_bfloat16* __restrict__ outb,        // mode 0: relu -> bf16 (global rows)
    float* __restrict__ outf,                 // mode 1: plain -> f32 (global rows)
    int mvalid, int node_base, int mode) {
  // [buf][op A=0/B=1][half][128][64] bf16 = 128 KiB
  __shared__ __hip_bfloat16 lds[2][2][2][128][64];

  const int t = threadIdx.x;
  const int lane = t & 63;
  const int wid = t >> 6;          // 0..7
  const int wave_m = wid >> 2;     // 0..1
  const int wave_n = wid & 3;      // 0..3
  const int ml = lane & 15;
  const int quad = lane >> 4;
  const int sw8 = ml & 7;
  const int lsub = lane >> 3;                 // 0..7  (stage: row within 8-row group)
  const int lg = (lane & 7) ^ lsub;           // stage: pre-swizzled source granule
  const int wrow = wid * 8;                   // stage: wave's dest row base

  // ---- bijective XCD swizzle (m204): 3 col-tiles of an m-panel -> same XCD
  const int nbx = gridDim.x;                  // 3
  const int nwg = nbx * gridDim.y;
  const int lid = blockIdx.y * nbx + blockIdx.x;   // HW dispatch order index
  const int q = nwg >> 3, r = nwg & 7;
  const int xcd = lid & 7, off = lid >> 3;
  const int swz = (xcd < r ? xcd * (q + 1) : r * (q + 1) + (xcd - r) * q) + off;
  const int m0 = (swz / nbx) * 256;
  const int n0 = (swz % nbx) * 256;

  // ---- per-lane source byte offsets for staging (row clamped -> always in-bounds;
  //      clamped (pad) rows only feed output rows masked at the epilogue)
  const char* cA = (const char*)A;
  const char* cF = (const char*)feat;
  const char* cB = (const char*)BT;
  uint32_t offA[2][2], offF[2][2], offB[2][2];   // [half][round]
#pragma unroll
  for (int h = 0; h < 2; ++h)
#pragma unroll
    for (int i = 0; i < 2; ++i) {
      const int srow = h * 128 + i * 64 + wrow + lsub;
      const int ar = imin(m0 + srow, mvalid - 1);
      const int fr = imin(node_base + m0 + srow, N_NODES - 1);
      offA[h][i] = (uint32_t)ar * (uint32_t)(GKA * 2) + (uint32_t)(lg * 16);
      offF[h][i] = (uint32_t)fr * (uint32_t)(DIM * 2) + (uint32_t)(lg * 16);
      offB[h][i] = (uint32_t)(n0 + srow) * (uint32_t)(GK * 2) + (uint32_t)(lg * 16);
    }

#define VMCNT(N) asm volatile("s_waitcnt vmcnt(" #N ")" ::: "memory")
#define LGKM0()  asm volatile("s_waitcnt lgkmcnt(0)" ::: "memory")
#define BAR()    asm volatile("s_barrier" ::: "memory")

#define STAGE_A(BUF, H, TS) do {                                                   \
    const char* _s0 = ((TS) < 96) ? cA + offA[H][0] + (size_t)(TS) * 128           \
                                  : cF + offF[H][0] + (size_t)((TS) - 96) * 128;   \
    const char* _s1 = ((TS) < 96) ? cA + offA[H][1] + (size_t)(TS) * 128           \
                                  : cF + offF[H][1] + (size_t)((TS) - 96) * 128;   \
    async_load16(_s0, &lds[BUF][0][H][wrow][0]);                                   \
    async_load16(_s1, &lds[BUF][0][H][64 + wrow][0]);                              \
  } while (0)

#define STAGE_B(BUF, H, TS) do {                                                   \
    async_load16(cB + offB[H][0] + (size_t)(TS) * 128, &lds[BUF][1][H][wrow][0]);  \
    async_load16(cB + offB[H][1] + (size_t)(TS) * 128, &lds[BUF][1][H][64 + wrow][0]); \
  } while (0)

#define LOAD_A(BUF, MH)                                                            \
  _Pragma("unroll") for (int mi = 0; mi < 4; ++mi)                                 \
  _Pragma("unroll") for (int kk = 0; kk < 2; ++kk)                                 \
    a[mi][kk] = *(const short8*)&lds[BUF][0][MH][wave_m * 64 + mi * 16 + ml]       \
                                              [((kk * 4 + quad) ^ sw8) * 8];

#define LOAD_B(BUF, NH, DST)                                                       \
  _Pragma("unroll") for (int ni = 0; ni < 2; ++ni)                                 \
  _Pragma("unroll") for (int kk = 0; kk < 2; ++kk)                                 \
    DST[ni][kk] = *(const short8*)&lds[BUF][1][NH][wave_n * 32 + ni * 16 + ml]     \
                                                 [((kk * 4 + quad) ^ sw8) * 8];

#define DO_MFMA(MH, NH, BREG)                                                      \
  _Pragma("unroll") for (int mi = 0; mi < 4; ++mi)                                 \
  _Pragma("unroll") for (int ni = 0; ni < 2; ++ni) {                               \
    acc[MH][NH][mi][ni] = __builtin_amdgcn_mfma_f32_16x16x32_bf16(                 \
        a[mi][0], BREG[ni][0], acc[MH][NH][mi][ni], 0, 0, 0);                      \
    acc[MH][NH][mi][ni] = __builtin_amdgcn_mfma_f32_16x16x32_bf16(                 \
        a[mi][1], BREG[ni][1], acc[MH][NH][mi][ni], 0, 0, 0);                      \
  }

  f32x4 acc[2][2][4][2] = {};   // [mh][nh][mi][ni]
  short8 a[4][2];               // current A half fragments  [mi][kk]
  short8 b0[2][2], b1[2][2];    // B half fragments, cached across phases

  // ---- prologue: stage A0(0),B0(0),A1(0),B1(0),A0(1),B0(1)  (12 loads)
  STAGE_A(0, 0, 0);
  STAGE_B(0, 0, 0);
  STAGE_A(0, 1, 0);
  STAGE_B(0, 1, 0);
  STAGE_A(1, 0, 1);
  STAGE_B(1, 0, 1);
  VMCNT(4);     // tile 0 fully landed; {A0(1),B0(1)} still in flight
  BAR();

#pragma unroll 2
  for (int T = 0; T < NT_TILES; ++T) {
    const int buf = T & 1;
    const int ts1 = (T + 1 < NT_TILES) ? T + 1 : NT_TILES - 1;  // clamped tail:
    const int ts2 = (T + 2 < NT_TILES) ? T + 2 : NT_TILES - 1;  // redundant, never read
    // ---- l0: (mh0, nh0)
    VMCNT(4);                      // retire A1,B1(T): needed at l1/l2
    LOAD_A(buf, 0);
    LOAD_B(buf, 0, b0);
    STAGE_A(buf ^ 1, 1, ts1);
    STAGE_B(buf ^ 1, 1, ts1);
    BAR(); LGKM0();
    __builtin_amdgcn_s_setprio(1);
    DO_MFMA(0, 0, b0);
    __builtin_amdgcn_s_setprio(0);
    BAR();
    // ---- l1: (mh0, nh1)
    LOAD_B(buf, 1, b1);
    BAR(); LGKM0();
    __builtin_amdgcn_s_setprio(1);
    DO_MFMA(0, 1, b1);
    __builtin_amdgcn_s_setprio(0);
    BAR();
    // ---- l2: (mh1, nh0)
    LOAD_A(buf, 1);
    STAGE_A(buf, 0, ts2);
    BAR(); LGKM0();
    __builtin_amdgcn_s_setprio(1);
    DO_MFMA(1, 0, b0);
    __builtin_amdgcn_s_setprio(0);
    BAR();
    // ---- l3: (mh1, nh1)
    VMCNT(6);                      // retire A0,B0(T+1): needed at next l0
    STAGE_B(buf, 0, ts2);
    BAR(); LGKM0();
    __builtin_amdgcn_s_setprio(1);
    DO_MFMA(1, 1, b1);
    __builtin_amdgcn_s_setprio(0);
    BAR();
  }
  VMCNT(0);     // drain tail stages before endpgm

#undef VMCNT
#undef LGKM0
#undef BAR
#undef STAGE_A
#undef STAGE_B
#undef LOAD_A
#undef LOAD_B
#undef DO_MFMA

  // ---- epilogue
  float bcol[2][2];
#pragma unroll
  for (int nh = 0; nh < 2; ++nh)
#pragma unroll
    for (int ni = 0; ni < 2; ++ni)
      bcol[nh][ni] = bias[n0 + nh * 128 + wave_n * 32 + ni * 16 + ml];

#pragma unroll
  for (int mh = 0; mh < 2; ++mh)
#pragma unroll
    for (int mi = 0; mi < 4; ++mi)
#pragma unroll
      for (int rr = 0; rr < 4; ++rr) {
        const int row = m0 + mh * 128 + wave_m * 64 + mi * 16 + quad * 4 + rr;
        if (row < mvalid) {
          const size_t orow = (size_t)(node_base + row) * DIM;
#pragma unroll
          for (int nh = 0; nh < 2; ++nh)
#pragma unroll
            for (int ni = 0; ni < 2; ++ni) {
              const int col = n0 + nh * 128 + wave_n * 32 + ni * 16 + ml;
              const float v = acc[mh][nh][mi][ni][rr] + bcol[nh][ni];
              if (mode == 0) outb[orow + col] = __float2bfloat16(fmaxf(v, 0.f));
              else           outf[orow + col] = v;
            }
        }
      }
}

// ---------------------------------------------------------------- launch
extern "C" void kernel_launch(void* const* d_in, const int* in_sizes, int n_in,
                              void* d_out, int out_size, void* d_ws, size_t ws_size,
                              hipStream_t stream) {
  const float* x     = (const float*)d_in[0];
  const int*   eidx  = (const int*)d_in[1];     // [2][E]
  const int*   etype = (const int*)d_in[2];
  const float* W1    = (const float*)d_in[3];
  const float* root1 = (const float*)d_in[4];
  const float* b1    = (const float*)d_in[5];
  const float* W2    = (const float*)d_in[6];
  const float* root2 = (const float*)d_in[7];
  const float* b2    = (const float*)d_in[8];
  float* out = (float*)d_out;
  const int* esrc_in = eidx;
  const int* edst_in = eidx + NEDGE;

  char* p = (char*)d_ws;
  auto alloc = [&](size_t bytes) -> char* {
    char* r = p;
    p += (bytes + 255) & ~(size_t)255;
    return r;
  };
  __hip_bfloat16* xb  = (__hip_bfloat16*)alloc((size_t)N_NODES * DIM * 2);
  __hip_bfloat16* hb  = (__hip_bfloat16*)alloc((size_t)N_NODES * DIM * 2);
  __hip_bfloat16* w1t = (__hip_bfloat16*)alloc((size_t)DIM * GK * 2);
  __hip_bfloat16* w2t = (__hip_bfloat16*)alloc((size_t)DIM * GK * 2);
  int* segcnt   = (int*)alloc((size_t)NSEG * 4);
  int* soffs    = (int*)alloc((size_t)(NSEG + 1) * 4);
  int* cursor   = (int*)alloc((size_t)NSEG * 4);
  int* partials = (int*)alloc(256 * 4);
  int* es       = (int*)alloc((size_t)NEDGE * 4);
  size_t used = (size_t)(p - (char*)d_ws);
  size_t remain = (ws_size > used) ? (ws_size - used) : 0;
  long long caprows_ll = (long long)(remain / ((size_t)GKA * 2));
  int caprows = (int)((caprows_ll / 128) * 128);
  if (caprows > 20096) caprows = 20096;   // 157*128
  if (caprows < 128) caprows = 128;
  __hip_bfloat16* Abuf = (__hip_bfloat16*)p;

  // --- segment CSR build (edges sorted by (dst, rel)) ---
  const int NB = (NSEG + 1023) / 1024;    // 157
  hipMemsetAsync(segcnt, 0, (size_t)NSEG * 4, stream);
  seg_count_kernel<<<(NEDGE + 255) / 256, 256, 0, stream>>>(edst_in, etype, segcnt, NEDGE);
  block_scan_kernel<<<NB, 1024, 0, stream>>>(segcnt, soffs, partials, NSEG);
  partial_scan_kernel<<<1, 64, 0, stream>>>(partials, NB);
  add_offsets_kernel<<<NB, 1024, 0, stream>>>(soffs, partials, cursor, NSEG);
  seg_scatter_kernel<<<(NEDGE + 255) / 256, 256, 0, stream>>>(esrc_in, edst_in, etype, cursor, es, NEDGE);

  // --- convert x, build transposed bf16 weights ---
  cvt_bf16_kernel<<<((N_NODES * DIM / 4) + 255) / 256, 256, 0, stream>>>(
      (const float4*)x, (ushort4*)xb, N_NODES * DIM / 4);
  dim3 tb(32, 8);
  transpose_w_kernel<<<dim3(DIM / 32, (NREL * DIM) / 32), tb, 0, stream>>>(W1, w1t, NREL * DIM, 0);
  transpose_w_kernel<<<dim3(DIM / 32, DIM / 32), tb, 0, stream>>>(root1, w1t, DIM, NREL * DIM);
  transpose_w_kernel<<<dim3(DIM / 32, (NREL * DIM) / 32), tb, 0, stream>>>(W2, w2t, NREL * DIM, 0);
  transpose_w_kernel<<<dim3(DIM / 32, DIM / 32), tb, 0, stream>>>(root2, w2t, DIM, NREL * DIM);

  // --- layer 1: h = relu([mean_r(x) | x] @ W1cat + b1) -> bf16 ---
  for (int base = 0; base < N_NODES; base += caprows) {
    int rows = N_NODES - base; if (rows > caprows) rows = caprows;
    int agrid = (rows + 4 * NPW - 1) / (4 * NPW);
    aggregate_kernel<<<agrid, 256, 0, stream>>>(xb, soffs, es, Abuf, base, rows);
    dim3 grid(DIM / 256, (rows + 255) / 256);
    gemm_kernel<<<grid, 512, 0, stream>>>(Abuf, xb, w1t, b1, hb, nullptr, rows, base, 0);
  }
  // --- layer 2: out = [mean_r(h) | h] @ W2cat + b2 -> f32 ---
  for (int base = 0; base < N_NODES; base += caprows) {
    int rows = N_NODES - base; if (rows > caprows) rows = caprows;
    int agrid = (rows + 4 * NPW - 1) / (4 * NPW);
    aggregate_kernel<<<agrid, 256, 0, stream>>>(hb, soffs, es, Abuf, base, rows);
    dim3 grid(DIM / 256, (rows + 255) / 256);
    gemm_kernel<<<grid, 512, 0, stream>>>(Abuf, hb, w2t, b2, nullptr, out, rows, base, 1);
  }
}

// Round 2
// 1124.408 us; speedup vs baseline: 1.0157x; 1.0157x over previous
//
#include <hip/hip_runtime.h>
#include <hip/hip_bf16.h>
#include <stdint.h>

#define N_NODES 20000
#define DIM     768
#define NREL    8
#define NEDGE   320000
#define NSEG    (N_NODES * NREL)   // 160000
#define GKA     6144   // NREL*DIM  (aggregated part of K)
#define GK      6912   // GKA + DIM (full K incl. root, materialized in Abuf)
#define NT_TILES (GK / 64)         // 108 K-tiles of 64
#define NPW     2      // nodes per wave in aggregate

typedef short short8 __attribute__((ext_vector_type(8)));
typedef float f32x4  __attribute__((ext_vector_type(4)));

__device__ __forceinline__ void async_load16(const void* g, void* l) {
  __builtin_amdgcn_global_load_lds((const __attribute__((address_space(1))) void*)g,
                                   (__attribute__((address_space(3))) void*)l,
                                   16, 0, 0);
}

__device__ __forceinline__ int imin(int a, int b) { return a < b ? a : b; }

__device__ __forceinline__ float bf_lo(uint32_t v) {
  return __builtin_bit_cast(float, v << 16);
}
__device__ __forceinline__ float bf_hi(uint32_t v) {
  return __builtin_bit_cast(float, v & 0xffff0000u);
}
__device__ __forceinline__ uint32_t pack_bf16x2(float a, float b) {
  uint32_t lo = __builtin_bit_cast(unsigned short, __float2bfloat16(a));
  uint32_t hi = __builtin_bit_cast(unsigned short, __float2bfloat16(b));
  return lo | (hi << 16);
}

// ---------------------------------------------------------------- segment CSR build
__global__ void seg_count_kernel(const int* __restrict__ dst, const int* __restrict__ et,
                                 int* __restrict__ segcnt, int e_cnt) {
  int e = blockIdx.x * 256 + threadIdx.x;
  if (e < e_cnt) atomicAdd(&segcnt[dst[e] * NREL + et[e]], 1);
}

__global__ void block_scan_kernel(const int* __restrict__ in, int* __restrict__ out,
                                  int* __restrict__ partials, int n) {
  __shared__ int wsum[16];
  const int t = threadIdx.x, lane = t & 63, wave = t >> 6;
  const int i = blockIdx.x * 1024 + t;
  int v = (i < n) ? in[i] : 0;
  int s = v;
#pragma unroll
  for (int off = 1; off < 64; off <<= 1) {
    int u = __shfl_up(s, off, 64);
    if (lane >= off) s += u;
  }
  if (lane == 63) wsum[wave] = s;
  __syncthreads();
  if (t < 16) {
    int w = wsum[t];
#pragma unroll
    for (int off = 1; off < 16; off <<= 1) {
      int u = __shfl_up(w, off, 64);
      if (t >= off) w += u;
    }
    wsum[t] = w;
  }
  __syncthreads();
  const int basew = (wave > 0) ? wsum[wave - 1] : 0;
  if (i < n) out[i] = basew + s - v;        // block-local exclusive
  if (t == 1023) partials[blockIdx.x] = wsum[15];
}

__global__ void partial_scan_kernel(int* __restrict__ partials, int nb) {
  const int lane = threadIdx.x & 63;
  int carry = 0;
  for (int base = 0; base < nb; base += 64) {
    const int i = base + lane;
    int v = (i < nb) ? partials[i] : 0;
    int s = v;
#pragma unroll
    for (int off = 1; off < 64; off <<= 1) {
      int u = __shfl_up(s, off, 64);
      if (lane >= off) s += u;
    }
    if (i < nb) partials[i] = carry + s - v;
    carry += __shfl(s, 63, 64);
  }
}

__global__ void add_offsets_kernel(int* __restrict__ soffs, const int* __restrict__ partials,
                                   int* __restrict__ cursor, int n) {
  const int i = blockIdx.x * 1024 + threadIdx.x;   // blockDim must be 1024
  if (i < n) {
    const int v = soffs[i] + partials[blockIdx.x];
    soffs[i] = v;
    cursor[i] = v;
  }
  if (i == 0) soffs[n] = NEDGE;
}

__global__ void seg_scatter_kernel(const int* __restrict__ src, const int* __restrict__ dst,
                                   const int* __restrict__ et, int* __restrict__ cursor,
                                   int* __restrict__ es, int e_cnt) {
  int e = blockIdx.x * 256 + threadIdx.x;
  if (e < e_cnt) {
    const int seg = dst[e] * NREL + et[e];
    const int p = atomicAdd(&cursor[seg], 1);
    es[p] = src[e];
  }
}

// ---------------------------------------------------------------- fp32 -> bf16
__global__ void cvt_bf16_kernel(const float4* __restrict__ in, ushort4* __restrict__ out, int n4) {
  int i = blockIdx.x * 256 + threadIdx.x;
  if (i < n4) {
    float4 f = in[i];
    ushort4 r;
    r.x = __builtin_bit_cast(unsigned short, __float2bfloat16(f.x));
    r.y = __builtin_bit_cast(unsigned short, __float2bfloat16(f.y));
    r.z = __builtin_bit_cast(unsigned short, __float2bfloat16(f.z));
    r.w = __builtin_bit_cast(unsigned short, __float2bfloat16(f.w));
    out[i] = r;
  }
}

// ------------------------------------------------- weight transpose (f32 src [rows][DIM] -> bf16 dst [DIM][GK])
__global__ void transpose_w_kernel(const float* __restrict__ src, __hip_bfloat16* __restrict__ dst,
                                   int rows, int col_off) {
  __shared__ float tile[32][33];
  const int c0 = blockIdx.x * 32;
  const int r0 = blockIdx.y * 32;
  const int tx = threadIdx.x, ty = threadIdx.y;  // 32x8
  for (int i = ty; i < 32; i += 8) {
    int r = r0 + i, c = c0 + tx;
    tile[i][tx] = (r < rows) ? src[(size_t)r * DIM + c] : 0.f;
  }
  __syncthreads();
  for (int i = ty; i < 32; i += 8) {
    int c = c0 + i, r = r0 + tx;
    if (r < rows)
      dst[(size_t)c * GK + col_off + r] = __float2bfloat16(tile[tx][i]);
  }
}

// ---------------------------------------------------------------- aggregation
// Rows of Abuf are now [GKA relation-means | root row] (stride GK) so the GEMM
// has one uniform A-stream.
__global__ __launch_bounds__(256) void aggregate_kernel(
    const __hip_bfloat16* __restrict__ feat,  // [N_NODES][DIM] bf16
    const int* __restrict__ soffs, const int* __restrict__ es,
    __hip_bfloat16* __restrict__ Abuf,        // [caprows][GK], chunk-local rows
    int node_base, int rows) {
  const int t = threadIdx.x;
  const int lane = t & 63;
  const int wave = t >> 6;
  const int boff = lane * 8;                  // byte offset within 512B third

  int nloc = (blockIdx.x * 4 + wave) * NPW;
  for (int it = 0; it < NPW; ++it, ++nloc) {
    if (nloc >= rows) return;
    const int n = node_base + nloc;
    char* Ab = (char*)(Abuf + (size_t)nloc * GK);
#pragma unroll
    for (int r = 0; r < NREL; ++r) {
      const int beg = soffs[n * NREL + r], end = soffs[n * NREL + r + 1];
      float acc[12];
#pragma unroll
      for (int i = 0; i < 12; ++i) acc[i] = 0.f;
      int e = beg;
      for (; e + 2 <= end; e += 2) {
        const int s0 = es[e], s1 = es[e + 1];
        const char* p0 = (const char*)(feat + (size_t)s0 * DIM) + boff;
        const char* p1 = (const char*)(feat + (size_t)s1 * DIM) + boff;
        const uint2 a0 = *(const uint2*)(p0);
        const uint2 a1 = *(const uint2*)(p0 + 512);
        const uint2 a2 = *(const uint2*)(p0 + 1024);
        const uint2 b0 = *(const uint2*)(p1);
        const uint2 b1 = *(const uint2*)(p1 + 512);
        const uint2 b2 = *(const uint2*)(p1 + 1024);
        acc[0]  += bf_lo(a0.x); acc[1]  += bf_hi(a0.x);
        acc[2]  += bf_lo(a0.y); acc[3]  += bf_hi(a0.y);
        acc[4]  += bf_lo(a1.x); acc[5]  += bf_hi(a1.x);
        acc[6]  += bf_lo(a1.y); acc[7]  += bf_hi(a1.y);
        acc[8]  += bf_lo(a2.x); acc[9]  += bf_hi(a2.x);
        acc[10] += bf_lo(a2.y); acc[11] += bf_hi(a2.y);
        acc[0]  += bf_lo(b0.x); acc[1]  += bf_hi(b0.x);
        acc[2]  += bf_lo(b0.y); acc[3]  += bf_hi(b0.y);
        acc[4]  += bf_lo(b1.x); acc[5]  += bf_hi(b1.x);
        acc[6]  += bf_lo(b1.y); acc[7]  += bf_hi(b1.y);
        acc[8]  += bf_lo(b2.x); acc[9]  += bf_hi(b2.x);
        acc[10] += bf_lo(b2.y); acc[11] += bf_hi(b2.y);
      }
      if (e < end) {
        const int s0 = es[e];
        const char* p0 = (const char*)(feat + (size_t)s0 * DIM) + boff;
        const uint2 a0 = *(const uint2*)(p0);
        const uint2 a1 = *(const uint2*)(p0 + 512);
        const uint2 a2 = *(const uint2*)(p0 + 1024);
        acc[0]  += bf_lo(a0.x); acc[1]  += bf_hi(a0.x);
        acc[2]  += bf_lo(a0.y); acc[3]  += bf_hi(a0.y);
        acc[4]  += bf_lo(a1.x); acc[5]  += bf_hi(a1.x);
        acc[6]  += bf_lo(a1.y); acc[7]  += bf_hi(a1.y);
        acc[8]  += bf_lo(a2.x); acc[9]  += bf_hi(a2.x);
        acc[10] += bf_lo(a2.y); acc[11] += bf_hi(a2.y);
      }
      const float inv = 1.f / fmaxf((float)(end - beg), 1.f);
      uint2 o0, o1, o2;
      o0.x = pack_bf16x2(acc[0] * inv, acc[1] * inv);
      o0.y = pack_bf16x2(acc[2] * inv, acc[3] * inv);
      o1.x = pack_bf16x2(acc[4] * inv, acc[5] * inv);
      o1.y = pack_bf16x2(acc[6] * inv, acc[7] * inv);
      o2.x = pack_bf16x2(acc[8] * inv, acc[9] * inv);
      o2.y = pack_bf16x2(acc[10] * inv, acc[11] * inv);
      char* dst = Ab + r * (DIM * 2);
      *(uint2*)(dst + boff) = o0;
      *(uint2*)(dst + boff + 512) = o1;
      *(uint2*)(dst + boff + 1024) = o2;
    }
    // append root row: Abuf[:, GKA:GK] = feat[n]
    const char* fsrc = (const char*)(feat + (size_t)n * DIM);
    char* fdst = Ab + GKA * 2;
    *(uint2*)(fdst + boff) = *(const uint2*)(fsrc + boff);
    *(uint2*)(fdst + boff + 512) = *(const uint2*)(fsrc + boff + 512);
    *(uint2*)(fdst + boff + 1024) = *(const uint2*)(fsrc + boff + 1024);
  }
}

// ---------------------------------------------------------------- GEMM (256^2, 8-wave, read-ahead pipeline)
// Region schedule (per tile T, buf = T&1); every MFMA's operands were ds_read
// >=1 region earlier, so LDS drain overlaps the previous MFMA cluster.
//   R0: vmcnt(8); read B1(T)->b1 (4)                     | MFMA l0 (aA,b0)
//   R1: vmcnt(4); stage A0,B0(T+2); read A1(T)->aB (8)   | MFMA l1 (aA,b1)
//   R2:           stage B1(T+2);    read A0(T+1)->aA (8) | MFMA l2 (aB,b0)
//   R3: vmcnt(8); stage A1(T+2);    read B0(T+1)->b0 (4) | MFMA l3 (aB,b1)
// No manual lgkmcnt: compiler emits counted waits at use points.
__global__ __launch_bounds__(512, 2) void gemm_kernel(
    const __hip_bfloat16* __restrict__ A,     // [rows][GK] chunk-local
    const __hip_bfloat16* __restrict__ BT,    // [DIM][GK]
    const float* __restrict__ bias,           // [DIM]
    __hip_bfloat16* __restrict__ outb,        // mode 0: relu -> bf16 (global rows)
    float* __restrict__ outf,                 // mode 1: plain -> f32 (global rows)
    int mvalid, int node_base, int mode) {
  __shared__ __hip_bfloat16 lds[2][2][2][128][64];  // [buf][op][half][row][col], 128 KiB

  const int t = threadIdx.x;
  const int lane = t & 63;
  const int wid = t >> 6;
  const int wave_m = wid >> 2;
  const int wave_n = wid & 3;
  const int ml = lane & 15;
  const int quad = lane >> 4;
  const int sw8 = ml & 7;
  const int lsub = lane >> 3;
  const int lg = (lane & 7) ^ lsub;
  const int wrow = wid * 8;

  const int nbx = gridDim.x;
  const int nwg = nbx * gridDim.y;
  const int lid = blockIdx.y * nbx + blockIdx.x;
  const int q = nwg >> 3, r = nwg & 7;
  const int xcd = lid & 7, off = lid >> 3;
  const int swz = (xcd < r ? xcd * (q + 1) : r * (q + 1) + (xcd - r) * q) + off;
  const int m0 = (swz / nbx) * 256;
  const int n0 = (swz % nbx) * 256;

  const char* cA = (const char*)A;
  const char* cB = (const char*)BT;
  uint32_t offA[2][2], offB[2][2];
#pragma unroll
  for (int h = 0; h < 2; ++h)
#pragma unroll
    for (int i = 0; i < 2; ++i) {
      const int srow = h * 128 + i * 64 + wrow + lsub;
      const int ar = imin(m0 + srow, mvalid - 1);
      offA[h][i] = (uint32_t)ar * (uint32_t)(GK * 2) + (uint32_t)(lg * 16);
      offB[h][i] = (uint32_t)(n0 + srow) * (uint32_t)(GK * 2) + (uint32_t)(lg * 16);
    }

#define VMCNT(N) asm volatile("s_waitcnt vmcnt(" #N ")" ::: "memory")
#define BAR()    asm volatile("s_barrier" ::: "memory")

#define STG_A(SB, H, TS) do {                                                      \
    const char* _p = cA + (size_t)(TS) * 128;                                      \
    async_load16(_p + offA[H][0], &lds[SB][0][H][wrow][0]);                        \
    async_load16(_p + offA[H][1], &lds[SB][0][H][64 + wrow][0]);                   \
  } while (0)

#define STG_B(SB, H, TS) do {                                                      \
    const char* _p = cB + (size_t)(TS) * 128;                                      \
    async_load16(_p + offB[H][0], &lds[SB][1][H][wrow][0]);                        \
    async_load16(_p + offB[H][1], &lds[SB][1][H][64 + wrow][0]);                   \
  } while (0)

#define LOAD_A(BUF, MH, DST)                                                       \
  _Pragma("unroll") for (int mi = 0; mi < 4; ++mi)                                 \
  _Pragma("unroll") for (int kk = 0; kk < 2; ++kk)                                 \
    DST[mi][kk] = *(const short8*)&lds[BUF][0][MH][wave_m * 64 + mi * 16 + ml]     \
                                                 [((kk * 4 + quad) ^ sw8) * 8];

#define LOAD_B(BUF, NH, DST)                                                       \
  _Pragma("unroll") for (int ni = 0; ni < 2; ++ni)                                 \
  _Pragma("unroll") for (int kk = 0; kk < 2; ++kk)                                 \
    DST[ni][kk] = *(const short8*)&lds[BUF][1][NH][wave_n * 32 + ni * 16 + ml]     \
                                                 [((kk * 4 + quad) ^ sw8) * 8];

#define DO_MFMA(MH, NH, AF, BF)                                                    \
  _Pragma("unroll") for (int mi = 0; mi < 4; ++mi)                                 \
  _Pragma("unroll") for (int ni = 0; ni < 2; ++ni) {                               \
    acc[MH][NH][mi][ni] = __builtin_amdgcn_mfma_f32_16x16x32_bf16(                 \
        AF[mi][0], BF[ni][0], acc[MH][NH][mi][ni], 0, 0, 0);                       \
    acc[MH][NH][mi][ni] = __builtin_amdgcn_mfma_f32_16x16x32_bf16(                 \
        AF[mi][1], BF[ni][1], acc[MH][NH][mi][ni], 0, 0, 0);                       \
  }

  f32x4 acc[2][2][4][2] = {};
  short8 aA[4][2], aB[4][2];
  short8 b0[2][2], b1[2][2];

  // prologue: stage tiles 0 and 1 (16 gloads), preload aA/b0 of tile 0
  STG_A(0, 0, 0); STG_B(0, 0, 0);
  STG_B(0, 1, 0);
  STG_A(0, 1, 0);
  STG_A(1, 0, 1); STG_B(1, 0, 1);
  STG_B(1, 1, 1);
  STG_A(1, 1, 1);
  VMCNT(12);
  BAR();
  LOAD_A(0, 0, aA);
  LOAD_B(0, 0, b0);
  VMCNT(8);
  BAR();

  for (int T = 0; T < NT_TILES; ++T) {
    const int buf = T & 1;
    const int ts2 = (T + 2 < NT_TILES) ? T + 2 : NT_TILES - 1;
    // R0
    VMCNT(8);
    LOAD_B(buf, 1, b1);
    BAR();
    __builtin_amdgcn_s_setprio(1);
    DO_MFMA(0, 0, aA, b0);
    __builtin_amdgcn_s_setprio(0);
    BAR();
    // R1
    VMCNT(4);
    STG_A(buf, 0, ts2);
    STG_B(buf, 0, ts2);
    LOAD_A(buf, 1, aB);
    BAR();
    __builtin_amdgcn_s_setprio(1);
    DO_MFMA(0, 1, aA, b1);
    __builtin_amdgcn_s_setprio(0);
    BAR();
    // R2
    STG_B(buf, 1, ts2);
    LOAD_A(buf ^ 1, 0, aA);
    BAR();
    __builtin_amdgcn_s_setprio(1);
    DO_MFMA(1, 0, aB, b0);
    __builtin_amdgcn_s_setprio(0);
    BAR();
    // R3
    VMCNT(8);
    STG_A(buf, 1, ts2);
    LOAD_B(buf ^ 1, 0, b0);
    BAR();
    __builtin_amdgcn_s_setprio(1);
    DO_MFMA(1, 1, aB, b1);
    __builtin_amdgcn_s_setprio(0);
    BAR();
  }
  VMCNT(0);

#undef VMCNT
#undef BAR
#undef STG_A
#undef STG_B
#undef LOAD_A
#undef LOAD_B
#undef DO_MFMA

  float bcol[2][2];
#pragma unroll
  for (int nh = 0; nh < 2; ++nh)
#pragma unroll
    for (int ni = 0; ni < 2; ++ni)
      bcol[nh][ni] = bias[n0 + nh * 128 + wave_n * 32 + ni * 16 + ml];

#pragma unroll
  for (int mh = 0; mh < 2; ++mh)
#pragma unroll
    for (int mi = 0; mi < 4; ++mi)
#pragma unroll
      for (int rr = 0; rr < 4; ++rr) {
        const int row = m0 + mh * 128 + wave_m * 64 + mi * 16 + quad * 4 + rr;
        if (row < mvalid) {
          const size_t orow = (size_t)(node_base + row) * DIM;
#pragma unroll
          for (int nh = 0; nh < 2; ++nh)
#pragma unroll
            for (int ni = 0; ni < 2; ++ni) {
              const int col = n0 + nh * 128 + wave_n * 32 + ni * 16 + ml;
              const float v = acc[mh][nh][mi][ni][rr] + bcol[nh][ni];
              if (mode == 0) outb[orow + col] = __float2bfloat16(fmaxf(v, 0.f));
              else           outf[orow + col] = v;
            }
        }
      }
}

// ---------------------------------------------------------------- launch
extern "C" void kernel_launch(void* const* d_in, const int* in_sizes, int n_in,
                              void* d_out, int out_size, void* d_ws, size_t ws_size,
                              hipStream_t stream) {
  const float* x     = (const float*)d_in[0];
  const int*   eidx  = (const int*)d_in[1];     // [2][E]
  const int*   etype = (const int*)d_in[2];
  const float* W1    = (const float*)d_in[3];
  const float* root1 = (const float*)d_in[4];
  const float* b1    = (const float*)d_in[5];
  const float* W2    = (const float*)d_in[6];
  const float* root2 = (const float*)d_in[7];
  const float* b2    = (const float*)d_in[8];
  float* out = (float*)d_out;
  const int* esrc_in = eidx;
  const int* edst_in = eidx + NEDGE;

  char* p = (char*)d_ws;
  auto alloc = [&](size_t bytes) -> char* {
    char* r = p;
    p += (bytes + 255) & ~(size_t)255;
    return r;
  };
  __hip_bfloat16* xb  = (__hip_bfloat16*)alloc((size_t)N_NODES * DIM * 2);
  __hip_bfloat16* hb  = (__hip_bfloat16*)alloc((size_t)N_NODES * DIM * 2);
  __hip_bfloat16* w1t = (__hip_bfloat16*)alloc((size_t)DIM * GK * 2);
  __hip_bfloat16* w2t = (__hip_bfloat16*)alloc((size_t)DIM * GK * 2);
  int* segcnt   = (int*)alloc((size_t)NSEG * 4);
  int* soffs    = (int*)alloc((size_t)(NSEG + 1) * 4);
  int* cursor   = (int*)alloc((size_t)NSEG * 4);
  int* partials = (int*)alloc(256 * 4);
  int* es       = (int*)alloc((size_t)NEDGE * 4);
  size_t used = (size_t)(p - (char*)d_ws);
  size_t remain = (ws_size > used) ? (ws_size - used) : 0;
  long long caprows_ll = (long long)(remain / ((size_t)GK * 2));
  int caprows = (int)((caprows_ll / 128) * 128);
  if (caprows > 20096) caprows = 20096;   // 157*128
  if (caprows < 128) caprows = 128;
  __hip_bfloat16* Abuf = (__hip_bfloat16*)p;

  // --- segment CSR build (edges sorted by (dst, rel)) ---
  const int NB = (NSEG + 1023) / 1024;    // 157
  hipMemsetAsync(segcnt, 0, (size_t)NSEG * 4, stream);
  seg_count_kernel<<<(NEDGE + 255) / 256, 256, 0, stream>>>(edst_in, etype, segcnt, NEDGE);
  block_scan_kernel<<<NB, 1024, 0, stream>>>(segcnt, soffs, partials, NSEG);
  partial_scan_kernel<<<1, 64, 0, stream>>>(partials, NB);
  add_offsets_kernel<<<NB, 1024, 0, stream>>>(soffs, partials, cursor, NSEG);
  seg_scatter_kernel<<<(NEDGE + 255) / 256, 256, 0, stream>>>(esrc_in, edst_in, etype, cursor, es, NEDGE);

  // --- convert x, build transposed bf16 weights ---
  cvt_bf16_kernel<<<((N_NODES * DIM / 4) + 255) / 256, 256, 0, stream>>>(
      (const float4*)x, (ushort4*)xb, N_NODES * DIM / 4);
  dim3 tb(32, 8);
  transpose_w_kernel<<<dim3(DIM / 32, (NREL * DIM) / 32), tb, 0, stream>>>(W1, w1t, NREL * DIM, 0);
  transpose_w_kernel<<<dim3(DIM / 32, DIM / 32), tb, 0, stream>>>(root1, w1t, DIM, NREL * DIM);
  transpose_w_kernel<<<dim3(DIM / 32, (NREL * DIM) / 32), tb, 0, stream>>>(W2, w2t, NREL * DIM, 0);
  transpose_w_kernel<<<dim3(DIM / 32, DIM / 32), tb, 0, stream>>>(root2, w2t, DIM, NREL * DIM);

  // --- layer 1: h = relu([mean_r(x) | x] @ W1cat + b1) -> bf16 ---
  for (int base = 0; base < N_NODES; base += caprows) {
    int rows = N_NODES - base; if (rows > caprows) rows = caprows;
    int agrid = (rows + 4 * NPW - 1) / (4 * NPW);
    aggregate_kernel<<<agrid, 256, 0, stream>>>(xb, soffs, es, Abuf, base, rows);
    dim3 grid(DIM / 256, (rows + 255) / 256);
    gemm_kernel<<<grid, 512, 0, stream>>>(Abuf, w1t, b1, hb, nullptr, rows, base, 0);
  }
  // --- layer 2: out = [mean_r(h) | h] @ W2cat + b2 -> f32 ---
  for (int base = 0; base < N_NODES; base += caprows) {
    int rows = N_NODES - base; if (rows > caprows) rows = caprows;
    int agrid = (rows + 4 * NPW - 1) / (4 * NPW);
    aggregate_kernel<<<agrid, 256, 0, stream>>>(hb, soffs, es, Abuf, base, rows);
    dim3 grid(DIM / 256, (rows + 255) / 256);
    gemm_kernel<<<grid, 512, 0, stream>>>(Abuf, w2t, b2, nullptr, out, rows, base, 1);
  }
}

// Round 5
// 939.084 us; speedup vs baseline: 1.2162x; 1.1973x over previous
//
#include <hip/hip_runtime.h>
#include <hip/hip_bf16.h>
#include <stdint.h>

#define N_NODES 20000
#define DIM     768
#define NREL    8
#define NEDGE   320000
#define NSEG    (N_NODES * NREL)   // 160000
#define NSLAB   9      // 8 relation slabs + root slab
#define KDIM    768    // GEMM K (input feature dim)
#define NKT     12     // K-tiles of 64 (768/64)
#define NPW     2      // nodes per wave in aggregate

typedef short short8 __attribute__((ext_vector_type(8)));
typedef float f32x4  __attribute__((ext_vector_type(4)));

__device__ __forceinline__ void async_load16(const void* g, void* l) {
  __builtin_amdgcn_global_load_lds((const __attribute__((address_space(1))) void*)g,
                                   (__attribute__((address_space(3))) void*)l,
                                   16, 0, 0);
}

__host__ __device__ __forceinline__ int imin(int a, int b) { return a < b ? a : b; }

__device__ __forceinline__ float bf_lo(uint32_t v) {
  return __builtin_bit_cast(float, v << 16);
}
__device__ __forceinline__ float bf_hi(uint32_t v) {
  return __builtin_bit_cast(float, v & 0xffff0000u);
}
__device__ __forceinline__ uint32_t pack_bf16x2(float a, float b) {
  uint32_t lo = __builtin_bit_cast(unsigned short, __float2bfloat16(a));
  uint32_t hi = __builtin_bit_cast(unsigned short, __float2bfloat16(b));
  return lo | (hi << 16);
}

// ---------------------------------------------------------------- segment CSR build
__global__ void seg_count_kernel(const int* __restrict__ dst, const int* __restrict__ et,
                                 int* __restrict__ segcnt, int e_cnt) {
  int e = blockIdx.x * 256 + threadIdx.x;
  if (e < e_cnt) atomicAdd(&segcnt[dst[e] * NREL + et[e]], 1);
}

__global__ void block_scan_kernel(const int* __restrict__ in, int* __restrict__ out,
                                  int* __restrict__ partials, int n) {
  __shared__ int wsum[16];
  const int t = threadIdx.x, lane = t & 63, wave = t >> 6;
  const int i = blockIdx.x * 1024 + t;
  int v = (i < n) ? in[i] : 0;
  int s = v;
#pragma unroll
  for (int off = 1; off < 64; off <<= 1) {
    int u = __shfl_up(s, off, 64);
    if (lane >= off) s += u;
  }
  if (lane == 63) wsum[wave] = s;
  __syncthreads();
  if (t < 16) {
    int w = wsum[t];
#pragma unroll
    for (int off = 1; off < 16; off <<= 1) {
      int u = __shfl_up(w, off, 64);
      if (t >= off) w += u;
    }
    wsum[t] = w;
  }
  __syncthreads();
  const int basew = (wave > 0) ? wsum[wave - 1] : 0;
  if (i < n) out[i] = basew + s - v;        // block-local exclusive
  if (t == 1023) partials[blockIdx.x] = wsum[15];
}

__global__ void partial_scan_kernel(int* __restrict__ partials, int nb) {
  const int lane = threadIdx.x & 63;
  int carry = 0;
  for (int base = 0; base < nb; base += 64) {
    const int i = base + lane;
    int v = (i < nb) ? partials[i] : 0;
    int s = v;
#pragma unroll
    for (int off = 1; off < 64; off <<= 1) {
      int u = __shfl_up(s, off, 64);
      if (lane >= off) s += u;
    }
    if (i < nb) partials[i] = carry + s - v;
    carry += __shfl(s, 63, 64);
  }
}

__global__ void add_offsets_kernel(int* __restrict__ soffs, const int* __restrict__ partials,
                                   int* __restrict__ cursor, int n) {
  const int i = blockIdx.x * 1024 + threadIdx.x;   // blockDim must be 1024
  if (i < n) {
    const int v = soffs[i] + partials[blockIdx.x];
    soffs[i] = v;
    cursor[i] = v;
  }
  if (i == 0) soffs[n] = NEDGE;
}

__global__ void seg_scatter_kernel(const int* __restrict__ src, const int* __restrict__ dst,
                                   const int* __restrict__ et, int* __restrict__ cursor,
                                   int* __restrict__ es, int e_cnt) {
  int e = blockIdx.x * 256 + threadIdx.x;
  if (e < e_cnt) {
    const int seg = dst[e] * NREL + et[e];
    const int p = atomicAdd(&cursor[seg], 1);
    es[p] = src[e];
  }
}

// ---------------------------------------------------------------- fp32 -> bf16
__global__ void cvt_bf16_kernel(const float4* __restrict__ in, ushort4* __restrict__ out, int n4) {
  int i = blockIdx.x * 256 + threadIdx.x;
  if (i < n4) {
    float4 f = in[i];
    ushort4 r;
    r.x = __builtin_bit_cast(unsigned short, __float2bfloat16(f.x));
    r.y = __builtin_bit_cast(unsigned short, __float2bfloat16(f.y));
    r.z = __builtin_bit_cast(unsigned short, __float2bfloat16(f.z));
    r.w = __builtin_bit_cast(unsigned short, __float2bfloat16(f.w));
    out[i] = r;
  }
}

// ------------------------------------------------- weight transpose
// dst[(s*768 + o)][i] = (s<8 ? W[s][i][o] : root[i][o]); dst rows length 768 (bf16)
__global__ void transpose_w2_kernel(const float* __restrict__ W, const float* __restrict__ root,
                                    __hip_bfloat16* __restrict__ dst) {
  __shared__ float tile[32][33];
  const int s = blockIdx.z;                  // 0..8
  const float* src = (s < 8) ? (W + (size_t)s * DIM * DIM) : root;
  const int c0 = blockIdx.x * 32;            // o
  const int r0 = blockIdx.y * 32;            // i
  const int tx = threadIdx.x, ty = threadIdx.y;  // 32x8
  for (int i = ty; i < 32; i += 8)
    tile[i][tx] = src[(size_t)(r0 + i) * DIM + c0 + tx];
  __syncthreads();
  for (int i = ty; i < 32; i += 8) {
    const int o = c0 + i, ii = r0 + tx;
    dst[((size_t)s * DIM + o) * KDIM + ii] = __float2bfloat16(tile[tx][i]);
  }
}

// ---------------------------------------------------------------- GEMM (256^2, 8-wave, read-ahead pipeline)
// Z[m, o] = sum_k X[m,k] * BT[o,k].  M=20000, N=zcols (group of slabs), K=768.
// Verified region schedule per tile T (buf=T&1):
//   R0: vmcnt(8); read B1(T)->b1 (4)                     | MFMA l0 (aA,b0)
//   R1: vmcnt(4); stage A0,B0(T+2); read A1(T)->aB (8)   | MFMA l1 (aA,b1)
//   R2:           stage B1(T+2);    read A0(T+1)->aA (8) | MFMA l2 (aB,b0)
//   R3: vmcnt(8); stage A1(T+2);    read B0(T+1)->b0 (4) | MFMA l3 (aB,b1)
__global__ __launch_bounds__(512, 2) void gemm_kernel(
    const __hip_bfloat16* __restrict__ A,     // [N_NODES][KDIM]
    const __hip_bfloat16* __restrict__ BT,    // [zcols][KDIM] (group slabs)
    __hip_bfloat16* __restrict__ Z,           // [N_NODES][zcols]
    int mvalid, int zcols) {
  __shared__ __hip_bfloat16 lds[2][2][2][128][64];  // [buf][op][half][row][col], 128 KiB

  const int t = threadIdx.x;
  const int lane = t & 63;
  const int wid = t >> 6;
  const int wave_m = wid >> 2;
  const int wave_n = wid & 3;
  const int ml = lane & 15;
  const int quad = lane >> 4;
  const int sw8 = ml & 7;
  const int lsub = lane >> 3;
  const int lg = (lane & 7) ^ lsub;
  const int wrow = wid * 8;

  const int nbx = gridDim.x;
  const int nwg = nbx * gridDim.y;
  const int lid = blockIdx.y * nbx + blockIdx.x;
  const int q = nwg >> 3, r = nwg & 7;
  const int xcd = lid & 7, off = lid >> 3;
  const int swz = (xcd < r ? xcd * (q + 1) : r * (q + 1) + (xcd - r) * q) + off;
  const int m0 = (swz / nbx) * 256;
  const int n0 = (swz % nbx) * 256;

  const char* cA = (const char*)A;
  const char* cB = (const char*)BT;
  uint32_t offA[2][2], offB[2][2];
#pragma unroll
  for (int h = 0; h < 2; ++h)
#pragma unroll
    for (int i = 0; i < 2; ++i) {
      const int srow = h * 128 + i * 64 + wrow + lsub;
      const int ar = imin(m0 + srow, mvalid - 1);
      offA[h][i] = (uint32_t)ar * (uint32_t)(KDIM * 2) + (uint32_t)(lg * 16);
      offB[h][i] = (uint32_t)(n0 + srow) * (uint32_t)(KDIM * 2) + (uint32_t)(lg * 16);
    }

#define VMCNT(N) asm volatile("s_waitcnt vmcnt(" #N ")" ::: "memory")
#define BAR()    asm volatile("s_barrier" ::: "memory")

#define STG_A(SB, H, TS) do {                                                      \
    const char* _p = cA + (size_t)(TS) * 128;                                      \
    async_load16(_p + offA[H][0], &lds[SB][0][H][wrow][0]);                        \
    async_load16(_p + offA[H][1], &lds[SB][0][H][64 + wrow][0]);                   \
  } while (0)

#define STG_B(SB, H, TS) do {                                                      \
    const char* _p = cB + (size_t)(TS) * 128;                                      \
    async_load16(_p + offB[H][0], &lds[SB][1][H][wrow][0]);                        \
    async_load16(_p + offB[H][1], &lds[SB][1][H][64 + wrow][0]);                   \
  } while (0)

#define LOAD_A(BUF, MH, DST)                                                       \
  _Pragma("unroll") for (int mi = 0; mi < 4; ++mi)                                 \
  _Pragma("unroll") for (int kk = 0; kk < 2; ++kk)                                 \
    DST[mi][kk] = *(const short8*)&lds[BUF][0][MH][wave_m * 64 + mi * 16 + ml]     \
                                                 [((kk * 4 + quad) ^ sw8) * 8];

#define LOAD_B(BUF, NH, DST)                                                       \
  _Pragma("unroll") for (int ni = 0; ni < 2; ++ni)                                 \
  _Pragma("unroll") for (int kk = 0; kk < 2; ++kk)                                 \
    DST[ni][kk] = *(const short8*)&lds[BUF][1][NH][wave_n * 32 + ni * 16 + ml]     \
                                                 [((kk * 4 + quad) ^ sw8) * 8];

#define DO_MFMA(MH, NH, AF, BF)                                                    \
  _Pragma("unroll") for (int mi = 0; mi < 4; ++mi)                                 \
  _Pragma("unroll") for (int ni = 0; ni < 2; ++ni) {                               \
    acc[MH][NH][mi][ni] = __builtin_amdgcn_mfma_f32_16x16x32_bf16(                 \
        AF[mi][0], BF[ni][0], acc[MH][NH][mi][ni], 0, 0, 0);                       \
    acc[MH][NH][mi][ni] = __builtin_amdgcn_mfma_f32_16x16x32_bf16(                 \
        AF[mi][1], BF[ni][1], acc[MH][NH][mi][ni], 0, 0, 0);                       \
  }

  f32x4 acc[2][2][4][2] = {};
  short8 aA[4][2], aB[4][2];
  short8 b0[2][2], b1[2][2];

  // prologue: stage tiles 0 and 1 (16 gloads), preload aA/b0 of tile 0
  STG_A(0, 0, 0); STG_B(0, 0, 0);
  STG_B(0, 1, 0);
  STG_A(0, 1, 0);
  STG_A(1, 0, 1); STG_B(1, 0, 1);
  STG_B(1, 1, 1);
  STG_A(1, 1, 1);
  VMCNT(12);
  BAR();
  LOAD_A(0, 0, aA);
  LOAD_B(0, 0, b0);
  VMCNT(8);
  BAR();

  for (int T = 0; T < NKT; ++T) {
    const int buf = T & 1;
    const int ts2 = (T + 2 < NKT) ? T + 2 : NKT - 1;
    // R0
    VMCNT(8);
    LOAD_B(buf, 1, b1);
    BAR();
    __builtin_amdgcn_s_setprio(1);
    DO_MFMA(0, 0, aA, b0);
    __builtin_amdgcn_s_setprio(0);
    BAR();
    // R1
    VMCNT(4);
    STG_A(buf, 0, ts2);
    STG_B(buf, 0, ts2);
    LOAD_A(buf, 1, aB);
    BAR();
    __builtin_amdgcn_s_setprio(1);
    DO_MFMA(0, 1, aA, b1);
    __builtin_amdgcn_s_setprio(0);
    BAR();
    // R2
    STG_B(buf, 1, ts2);
    LOAD_A(buf ^ 1, 0, aA);
    BAR();
    __builtin_amdgcn_s_setprio(1);
    DO_MFMA(1, 0, aB, b0);
    __builtin_amdgcn_s_setprio(0);
    BAR();
    // R3
    VMCNT(8);
    STG_A(buf, 1, ts2);
    LOAD_B(buf ^ 1, 0, b0);
    BAR();
    __builtin_amdgcn_s_setprio(1);
    DO_MFMA(1, 1, aB, b1);
    __builtin_amdgcn_s_setprio(0);
    BAR();
  }
  VMCNT(0);

#undef VMCNT
#undef BAR
#undef STG_A
#undef STG_B
#undef LOAD_A
#undef LOAD_B
#undef DO_MFMA

#pragma unroll
  for (int mh = 0; mh < 2; ++mh)
#pragma unroll
    for (int mi = 0; mi < 4; ++mi)
#pragma unroll
      for (int rr = 0; rr < 4; ++rr) {
        const int row = m0 + mh * 128 + wave_m * 64 + mi * 16 + quad * 4 + rr;
        if (row < mvalid) {
          const size_t orow = (size_t)row * (size_t)zcols;
#pragma unroll
          for (int nh = 0; nh < 2; ++nh)
#pragma unroll
            for (int ni = 0; ni < 2; ++ni) {
              const int col = n0 + nh * 128 + wave_n * 32 + ni * 16 + ml;
              Z[orow + col] = __float2bfloat16(acc[mh][nh][mi][ni][rr]);
            }
        }
      }
}

// ---------------------------------------------------------------- aggregation over a slab group of Z
// acc starts as bias (first group) or accf[n] (later groups); accumulates
// sum_r mean_{j in N_r(n)} Z[j][slab r] for relations in this group; last group
// also adds the root slab and finalizes (mode 0: relu->bf16; mode 1: f32 accf==out).
__device__ __forceinline__ void seg_mean_add(const char* cZ, size_t zrb, uint32_t colb,
                                             int beg, int end, int boff, float* acc,
                                             const int* es) {
  float s[12];
#pragma unroll
  for (int i = 0; i < 12; ++i) s[i] = 0.f;
  int e = beg;
  for (; e + 2 <= end; e += 2) {
    const int s0 = es[e], s1 = es[e + 1];
    const char* p0 = cZ + (size_t)s0 * zrb + colb + boff;
    const char* p1 = cZ + (size_t)s1 * zrb + colb + boff;
    const uint2 a0 = *(const uint2*)(p0);
    const uint2 a1 = *(const uint2*)(p0 + 512);
    const uint2 a2 = *(const uint2*)(p0 + 1024);
    const uint2 c0 = *(const uint2*)(p1);
    const uint2 c1 = *(const uint2*)(p1 + 512);
    const uint2 c2 = *(const uint2*)(p1 + 1024);
    s[0]  += bf_lo(a0.x); s[1]  += bf_hi(a0.x);
    s[2]  += bf_lo(a0.y); s[3]  += bf_hi(a0.y);
    s[4]  += bf_lo(a1.x); s[5]  += bf_hi(a1.x);
    s[6]  += bf_lo(a1.y); s[7]  += bf_hi(a1.y);
    s[8]  += bf_lo(a2.x); s[9]  += bf_hi(a2.x);
    s[10] += bf_lo(a2.y); s[11] += bf_hi(a2.y);
    s[0]  += bf_lo(c0.x); s[1]  += bf_hi(c0.x);
    s[2]  += bf_lo(c0.y); s[3]  += bf_hi(c0.y);
    s[4]  += bf_lo(c1.x); s[5]  += bf_hi(c1.x);
    s[6]  += bf_lo(c1.y); s[7]  += bf_hi(c1.y);
    s[8]  += bf_lo(c2.x); s[9]  += bf_hi(c2.x);
    s[10] += bf_lo(c2.y); s[11] += bf_hi(c2.y);
  }
  if (e < end) {
    const int s0 = es[e];
    const char* p0 = cZ + (size_t)s0 * zrb + colb + boff;
    const uint2 a0 = *(const uint2*)(p0);
    const uint2 a1 = *(const uint2*)(p0 + 512);
    const uint2 a2 = *(const uint2*)(p0 + 1024);
    s[0]  += bf_lo(a0.x); s[1]  += bf_hi(a0.x);
    s[2]  += bf_lo(a0.y); s[3]  += bf_hi(a0.y);
    s[4]  += bf_lo(a1.x); s[5]  += bf_hi(a1.x);
    s[6]  += bf_lo(a1.y); s[7]  += bf_hi(a1.y);
    s[8]  += bf_lo(a2.x); s[9]  += bf_hi(a2.x);
    s[10] += bf_lo(a2.y); s[11] += bf_hi(a2.y);
  }
  const float inv = 1.f / (float)(end - beg);
#pragma unroll
  for (int i = 0; i < 12; ++i) acc[i] += s[i] * inv;
}

__global__ __launch_bounds__(256) void aggregate2_kernel(
    const __hip_bfloat16* __restrict__ Z,   // [N_NODES][zcols]
    int zcols,
    const int* __restrict__ soffs, const int* __restrict__ es,
    const float* __restrict__ bias,         // [DIM] f32
    float* __restrict__ accf,               // [N_NODES][DIM] f32 accumulator (== out)
    __hip_bfloat16* __restrict__ outb,      // final bf16 dst (mode 0)
    int g0, int ns, int first, int last, int mode) {
  const int t = threadIdx.x;
  const int lane = t & 63;
  const int wave = t >> 6;
  const int boff = lane * 8;
  const char* cZ = (const char*)Z;
  const size_t zrb = (size_t)zcols * 2;

  int n = (blockIdx.x * 4 + wave) * NPW;
  for (int it = 0; it < NPW; ++it, ++n) {
    if (n >= N_NODES) return;
    float acc[12];
    if (first) {
      const float4 bv0 = *(const float4*)(bias + lane * 4);
      const float4 bv1 = *(const float4*)(bias + 256 + lane * 4);
      const float4 bv2 = *(const float4*)(bias + 512 + lane * 4);
      acc[0] = bv0.x; acc[1] = bv0.y; acc[2] = bv0.z; acc[3] = bv0.w;
      acc[4] = bv1.x; acc[5] = bv1.y; acc[6] = bv1.z; acc[7] = bv1.w;
      acc[8] = bv2.x; acc[9] = bv2.y; acc[10] = bv2.z; acc[11] = bv2.w;
    } else {
      const float* ap = accf + (size_t)n * DIM;
      const float4 v0 = *(const float4*)(ap + lane * 4);
      const float4 v1 = *(const float4*)(ap + 256 + lane * 4);
      const float4 v2 = *(const float4*)(ap + 512 + lane * 4);
      acc[0] = v0.x; acc[1] = v0.y; acc[2] = v0.z; acc[3] = v0.w;
      acc[4] = v1.x; acc[5] = v1.y; acc[6] = v1.z; acc[7] = v1.w;
      acc[8] = v2.x; acc[9] = v2.y; acc[10] = v2.z; acc[11] = v2.w;
    }
    const int rend = imin(g0 + ns, NREL);    // relation slabs in this group
    for (int r = g0; r < rend; ++r) {
      const int beg = soffs[n * NREL + r], end = soffs[n * NREL + r + 1];
      if (beg == end) continue;
      seg_mean_add(cZ, zrb, (uint32_t)(r - g0) * (DIM * 2), beg, end, boff, acc, es);
    }
    if (last) {
      // root slab (index 8) lives in the last group at chunk col (8-g0)*DIM
      const char* zr = cZ + (size_t)n * zrb + (size_t)(NSLAB - 1 - g0) * (DIM * 2);
      const uint2 r0 = *(const uint2*)(zr + boff);
      const uint2 r1 = *(const uint2*)(zr + boff + 512);
      const uint2 r2 = *(const uint2*)(zr + boff + 1024);
      acc[0] += bf_lo(r0.x); acc[1] += bf_hi(r0.x);
      acc[2] += bf_lo(r0.y); acc[3] += bf_hi(r0.y);
      acc[4] += bf_lo(r1.x); acc[5] += bf_hi(r1.x);
      acc[6] += bf_lo(r1.y); acc[7] += bf_hi(r1.y);
      acc[8] += bf_lo(r2.x); acc[9] += bf_hi(r2.x);
      acc[10] += bf_lo(r2.y); acc[11] += bf_hi(r2.y);
    }
    if (!last) {
      float* ap = accf + (size_t)n * DIM;
      float4 v0, v1, v2;
      v0.x = acc[0]; v0.y = acc[1]; v0.z = acc[2]; v0.w = acc[3];
      v1.x = acc[4]; v1.y = acc[5]; v1.z = acc[6]; v1.w = acc[7];
      v2.x = acc[8]; v2.y = acc[9]; v2.z = acc[10]; v2.w = acc[11];
      *(float4*)(ap + lane * 4) = v0;
      *(float4*)(ap + 256 + lane * 4) = v1;
      *(float4*)(ap + 512 + lane * 4) = v2;
    } else if (mode == 0) {
      char* dst = (char*)outb + (size_t)n * (DIM * 2);
      uint2 o0, o1, o2;
      o0.x = pack_bf16x2(fmaxf(acc[0], 0.f), fmaxf(acc[1], 0.f));
      o0.y = pack_bf16x2(fmaxf(acc[2], 0.f), fmaxf(acc[3], 0.f));
      o1.x = pack_bf16x2(fmaxf(acc[4], 0.f), fmaxf(acc[5], 0.f));
      o1.y = pack_bf16x2(fmaxf(acc[6], 0.f), fmaxf(acc[7], 0.f));
      o2.x = pack_bf16x2(fmaxf(acc[8], 0.f), fmaxf(acc[9], 0.f));
      o2.y = pack_bf16x2(fmaxf(acc[10], 0.f), fmaxf(acc[11], 0.f));
      *(uint2*)(dst + boff) = o0;
      *(uint2*)(dst + boff + 512) = o1;
      *(uint2*)(dst + boff + 1024) = o2;
    } else {
      float* ap = accf + (size_t)n * DIM;   // accf == out: final f32 store
      float4 v0, v1, v2;
      v0.x = acc[0]; v0.y = acc[1]; v0.z = acc[2]; v0.w = acc[3];
      v1.x = acc[4]; v1.y = acc[5]; v1.z = acc[6]; v1.w = acc[7];
      v2.x = acc[8]; v2.y = acc[9]; v2.z = acc[10]; v2.w = acc[11];
      *(float4*)(ap + lane * 4) = v0;
      *(float4*)(ap + 256 + lane * 4) = v1;
      *(float4*)(ap + 512 + lane * 4) = v2;
    }
  }
}

// ---------------------------------------------------------------- launch
extern "C" void kernel_launch(void* const* d_in, const int* in_sizes, int n_in,
                              void* d_out, int out_size, void* d_ws, size_t ws_size,
                              hipStream_t stream) {
  const float* x     = (const float*)d_in[0];
  const int*   eidx  = (const int*)d_in[1];     // [2][E]
  const int*   etype = (const int*)d_in[2];
  const float* W1    = (const float*)d_in[3];
  const float* root1 = (const float*)d_in[4];
  const float* b1    = (const float*)d_in[5];
  const float* W2    = (const float*)d_in[6];
  const float* root2 = (const float*)d_in[7];
  const float* b2    = (const float*)d_in[8];
  float* out = (float*)d_out;
  const int* esrc_in = eidx;
  const int* edst_in = eidx + NEDGE;

  char* p = (char*)d_ws;
  auto alloc = [&](size_t bytes) -> char* {
    char* r = p;
    p += (bytes + 255) & ~(size_t)255;
    return r;
  };
  // fixed allocations (~44.5 MB): one weight buffer (re-transposed between
  // layers), CSR scratch, xb (hb aliases xb -- the only hb write is the final
  // layer-1 aggregate, stream-ordered after every gemm read of xb).
  __hip_bfloat16* wt  = (__hip_bfloat16*)alloc((size_t)NSLAB * DIM * KDIM * 2);
  int* segcnt   = (int*)alloc((size_t)NSEG * 4);
  int* soffs    = (int*)alloc((size_t)(NSEG + 1) * 4);
  int* cursor   = (int*)alloc((size_t)NSEG * 4);
  int* partials = (int*)alloc(256 * 4);
  int* es       = (int*)alloc((size_t)NEDGE * 4);
  __hip_bfloat16* xb  = (__hip_bfloat16*)alloc((size_t)N_NODES * DIM * 2);
  __hip_bfloat16* hb  = xb;

  // adaptive slab chunking for Z
  const size_t used = (size_t)(p - (char*)d_ws);
  const size_t remain = (ws_size > used) ? (ws_size - used) : 0;
  const size_t slab_bytes = (size_t)N_NODES * DIM * 2;   // 30.72 MB
  int S = (int)(remain / slab_bytes);
  if (S > NSLAB) S = NSLAB;
  if (S < 1) S = 1;
  __hip_bfloat16* Z = (__hip_bfloat16*)p;

  // --- segment CSR build (edges sorted by (dst, rel)) ---
  const int NB = (NSEG + 1023) / 1024;    // 157
  (void)hipMemsetAsync(segcnt, 0, (size_t)NSEG * 4, stream);
  seg_count_kernel<<<(NEDGE + 255) / 256, 256, 0, stream>>>(edst_in, etype, segcnt, NEDGE);
  block_scan_kernel<<<NB, 1024, 0, stream>>>(segcnt, soffs, partials, NSEG);
  partial_scan_kernel<<<1, 64, 0, stream>>>(partials, NB);
  add_offsets_kernel<<<NB, 1024, 0, stream>>>(soffs, partials, cursor, NSEG);
  seg_scatter_kernel<<<(NEDGE + 255) / 256, 256, 0, stream>>>(esrc_in, edst_in, etype, cursor, es, NEDGE);

  // --- convert x, transpose W1 ---
  cvt_bf16_kernel<<<((N_NODES * DIM / 4) + 255) / 256, 256, 0, stream>>>(
      (const float4*)x, (ushort4*)xb, N_NODES * DIM / 4);
  dim3 tb(32, 8);
  transpose_w2_kernel<<<dim3(DIM / 32, DIM / 32, NSLAB), tb, 0, stream>>>(W1, root1, wt);

  const int agrid = (N_NODES + 4 * NPW - 1) / (4 * NPW);    // 2500

  // --- layer 1: Z = xb @ W1cat^T (slab groups); h = relu(agg(Z) + b1) -> hb ---
  for (int g0 = 0; g0 < NSLAB; g0 += S) {
    const int ns = imin(S, NSLAB - g0);
    const int zc = ns * DIM;
    dim3 gg(zc / 256, (N_NODES + 255) / 256);
    gemm_kernel<<<gg, 512, 0, stream>>>(xb, wt + (size_t)g0 * DIM * KDIM, Z, N_NODES, zc);
    aggregate2_kernel<<<agrid, 256, 0, stream>>>(Z, zc, soffs, es, b1, out, hb,
                                                 g0, ns, g0 == 0, g0 + ns == NSLAB, 0);
  }

  // --- re-transpose weights for layer 2 (after last layer-1 gemm read of wt) ---
  transpose_w2_kernel<<<dim3(DIM / 32, DIM / 32, NSLAB), tb, 0, stream>>>(W2, root2, wt);

  // --- layer 2: Z = hb @ W2cat^T ; out = agg(Z) + b2 (accf == out) ---
  for (int g0 = 0; g0 < NSLAB; g0 += S) {
    const int ns = imin(S, NSLAB - g0);
    const int zc = ns * DIM;
    dim3 gg(zc / 256, (N_NODES + 255) / 256);
    gemm_kernel<<<gg, 512, 0, stream>>>(hb, wt + (size_t)g0 * DIM * KDIM, Z, N_NODES, zc);
    aggregate2_kernel<<<agrid, 256, 0, stream>>>(Z, zc, soffs, es, b2, out, nullptr,
                                                 g0, ns, g0 == 0, g0 + ns == NSLAB, 1);
  }
}

// Round 6
// 914.516 us; speedup vs baseline: 1.2488x; 1.0269x over previous
//
#include <hip/hip_runtime.h>
#include <hip/hip_bf16.h>
#include <stdint.h>

#define N_NODES 20000
#define DIM     768
#define NREL    8
#define NEDGE   320000
#define NSEG    (N_NODES * NREL)   // 160000
#define NSLAB   9      // 8 relation slabs + root slab
#define KDIM    768    // GEMM K (input feature dim)
#define NKT     12     // K-tiles of 64 (768/64)
#define NPW     2      // nodes per wave in aggregate

typedef short short8 __attribute__((ext_vector_type(8)));
typedef float f32x4  __attribute__((ext_vector_type(4)));

__device__ __forceinline__ void async_load16(const void* g, void* l) {
  __builtin_amdgcn_global_load_lds((const __attribute__((address_space(1))) void*)g,
                                   (__attribute__((address_space(3))) void*)l,
                                   16, 0, 0);
}

__host__ __device__ __forceinline__ int imin(int a, int b) { return a < b ? a : b; }

__device__ __forceinline__ float bf_lo(uint32_t v) {
  return __builtin_bit_cast(float, v << 16);
}
__device__ __forceinline__ float bf_hi(uint32_t v) {
  return __builtin_bit_cast(float, v & 0xffff0000u);
}
__device__ __forceinline__ uint32_t pack_bf16x2(float a, float b) {
  uint32_t lo = __builtin_bit_cast(unsigned short, __float2bfloat16(a));
  uint32_t hi = __builtin_bit_cast(unsigned short, __float2bfloat16(b));
  return lo | (hi << 16);
}

// ---------------------------------------------------------------- segment CSR build
__global__ void seg_count_kernel(const int* __restrict__ dst, const int* __restrict__ et,
                                 int* __restrict__ segcnt, int e_cnt) {
  int e = blockIdx.x * 256 + threadIdx.x;
  if (e < e_cnt) atomicAdd(&segcnt[dst[e] * NREL + et[e]], 1);
}

__global__ void block_scan_kernel(const int* __restrict__ in, int* __restrict__ out,
                                  int* __restrict__ partials, int n) {
  __shared__ int wsum[16];
  const int t = threadIdx.x, lane = t & 63, wave = t >> 6;
  const int i = blockIdx.x * 1024 + t;
  int v = (i < n) ? in[i] : 0;
  int s = v;
#pragma unroll
  for (int off = 1; off < 64; off <<= 1) {
    int u = __shfl_up(s, off, 64);
    if (lane >= off) s += u;
  }
  if (lane == 63) wsum[wave] = s;
  __syncthreads();
  if (t < 16) {
    int w = wsum[t];
#pragma unroll
    for (int off = 1; off < 16; off <<= 1) {
      int u = __shfl_up(w, off, 64);
      if (t >= off) w += u;
    }
    wsum[t] = w;
  }
  __syncthreads();
  const int basew = (wave > 0) ? wsum[wave - 1] : 0;
  if (i < n) out[i] = basew + s - v;        // block-local exclusive
  if (t == 1023) partials[blockIdx.x] = wsum[15];
}

__global__ void partial_scan_kernel(int* __restrict__ partials, int nb) {
  const int lane = threadIdx.x & 63;
  int carry = 0;
  for (int base = 0; base < nb; base += 64) {
    const int i = base + lane;
    int v = (i < nb) ? partials[i] : 0;
    int s = v;
#pragma unroll
    for (int off = 1; off < 64; off <<= 1) {
      int u = __shfl_up(s, off, 64);
      if (lane >= off) s += u;
    }
    if (i < nb) partials[i] = carry + s - v;
    carry += __shfl(s, 63, 64);
  }
}

__global__ void add_offsets_kernel(int* __restrict__ soffs, const int* __restrict__ partials,
                                   int* __restrict__ cursor, int n) {
  const int i = blockIdx.x * 1024 + threadIdx.x;   // blockDim must be 1024
  if (i < n) {
    const int v = soffs[i] + partials[blockIdx.x];
    soffs[i] = v;
    cursor[i] = v;
  }
  if (i == 0) soffs[n] = NEDGE;
}

__global__ void seg_scatter_kernel(const int* __restrict__ src, const int* __restrict__ dst,
                                   const int* __restrict__ et, int* __restrict__ cursor,
                                   int* __restrict__ es, int e_cnt) {
  int e = blockIdx.x * 256 + threadIdx.x;
  if (e < e_cnt) {
    const int seg = dst[e] * NREL + et[e];
    const int p = atomicAdd(&cursor[seg], 1);
    es[p] = src[e];
  }
}

// ---------------------------------------------------------------- fp32 -> bf16
__global__ void cvt_bf16_kernel(const float4* __restrict__ in, ushort4* __restrict__ out, int n4) {
  int i = blockIdx.x * 256 + threadIdx.x;
  if (i < n4) {
    float4 f = in[i];
    ushort4 r;
    r.x = __builtin_bit_cast(unsigned short, __float2bfloat16(f.x));
    r.y = __builtin_bit_cast(unsigned short, __float2bfloat16(f.y));
    r.z = __builtin_bit_cast(unsigned short, __float2bfloat16(f.z));
    r.w = __builtin_bit_cast(unsigned short, __float2bfloat16(f.w));
    out[i] = r;
  }
}

// ------------------------------------------------- weight transpose
// dst[(s*768 + o)][i] = (s<8 ? W[s][i][o] : root[i][o]); dst rows length 768 (bf16)
__global__ void transpose_w2_kernel(const float* __restrict__ W, const float* __restrict__ root,
                                    __hip_bfloat16* __restrict__ dst) {
  __shared__ float tile[32][33];
  const int s = blockIdx.z;                  // 0..8
  const float* src = (s < 8) ? (W + (size_t)s * DIM * DIM) : root;
  const int c0 = blockIdx.x * 32;            // o
  const int r0 = blockIdx.y * 32;            // i
  const int tx = threadIdx.x, ty = threadIdx.y;  // 32x8
  for (int i = ty; i < 32; i += 8)
    tile[i][tx] = src[(size_t)(r0 + i) * DIM + c0 + tx];
  __syncthreads();
  for (int i = ty; i < 32; i += 8) {
    const int o = c0 + i, ii = r0 + tx;
    dst[((size_t)s * DIM + o) * KDIM + ii] = __float2bfloat16(tile[tx][i]);
  }
}

// ---------------------------------------------------------------- GEMM (256^2, 8-wave, read-ahead pipeline)
// Z[m, o] = sum_k X[m,k] * BT[o,k].  M=20000, N=zcols (group of slabs), K=768.
// Verified region schedule per tile T (buf=T&1):
//   R0: vmcnt(8); read B1(T)->b1 (4)                     | MFMA l0 (aA,b0)
//   R1: vmcnt(4); stage A0,B0(T+2); read A1(T)->aB (8)   | MFMA l1 (aA,b1)
//   R2:           stage B1(T+2);    read A0(T+1)->aA (8) | MFMA l2 (aB,b0)
//   R3: vmcnt(8); stage A1(T+2);    read B0(T+1)->b0 (4) | MFMA l3 (aB,b1)
// Epilogue: stage C tile in LDS (reusing pipeline buffer) and write back with
// 16B/lane stores, 512B-contiguous per row -> no partial-line RFO on Z.
__global__ __launch_bounds__(512, 2) void gemm_kernel(
    const __hip_bfloat16* __restrict__ A,     // [N_NODES][KDIM]
    const __hip_bfloat16* __restrict__ BT,    // [zcols][KDIM] (group slabs)
    __hip_bfloat16* __restrict__ Z,           // [N_NODES][zcols]
    int mvalid, int zcols) {
  __shared__ __hip_bfloat16 lds[2][2][2][128][64];  // [buf][op][half][row][col], 128 KiB

  const int t = threadIdx.x;
  const int lane = t & 63;
  const int wid = t >> 6;
  const int wave_m = wid >> 2;
  const int wave_n = wid & 3;
  const int ml = lane & 15;
  const int quad = lane >> 4;
  const int sw8 = ml & 7;
  const int lsub = lane >> 3;
  const int lg = (lane & 7) ^ lsub;
  const int wrow = wid * 8;

  const int nbx = gridDim.x;
  const int nwg = nbx * gridDim.y;
  const int lid = blockIdx.y * nbx + blockIdx.x;
  const int q = nwg >> 3, r = nwg & 7;
  const int xcd = lid & 7, off = lid >> 3;
  const int swz = (xcd < r ? xcd * (q + 1) : r * (q + 1) + (xcd - r) * q) + off;
  const int m0 = (swz / nbx) * 256;
  const int n0 = (swz % nbx) * 256;

  const char* cA = (const char*)A;
  const char* cB = (const char*)BT;
  uint32_t offA[2][2], offB[2][2];
#pragma unroll
  for (int h = 0; h < 2; ++h)
#pragma unroll
    for (int i = 0; i < 2; ++i) {
      const int srow = h * 128 + i * 64 + wrow + lsub;
      const int ar = imin(m0 + srow, mvalid - 1);
      offA[h][i] = (uint32_t)ar * (uint32_t)(KDIM * 2) + (uint32_t)(lg * 16);
      offB[h][i] = (uint32_t)(n0 + srow) * (uint32_t)(KDIM * 2) + (uint32_t)(lg * 16);
    }

#define VMCNT(N) asm volatile("s_waitcnt vmcnt(" #N ")" ::: "memory")
#define LGKM0()  asm volatile("s_waitcnt lgkmcnt(0)" ::: "memory")
#define BAR()    asm volatile("s_barrier" ::: "memory")

#define STG_A(SB, H, TS) do {                                                      \
    const char* _p = cA + (size_t)(TS) * 128;                                      \
    async_load16(_p + offA[H][0], &lds[SB][0][H][wrow][0]);                        \
    async_load16(_p + offA[H][1], &lds[SB][0][H][64 + wrow][0]);                   \
  } while (0)

#define STG_B(SB, H, TS) do {                                                      \
    const char* _p = cB + (size_t)(TS) * 128;                                      \
    async_load16(_p + offB[H][0], &lds[SB][1][H][wrow][0]);                        \
    async_load16(_p + offB[H][1], &lds[SB][1][H][64 + wrow][0]);                   \
  } while (0)

#define LOAD_A(BUF, MH, DST)                                                       \
  _Pragma("unroll") for (int mi = 0; mi < 4; ++mi)                                 \
  _Pragma("unroll") for (int kk = 0; kk < 2; ++kk)                                 \
    DST[mi][kk] = *(const short8*)&lds[BUF][0][MH][wave_m * 64 + mi * 16 + ml]     \
                                                 [((kk * 4 + quad) ^ sw8) * 8];

#define LOAD_B(BUF, NH, DST)                                                       \
  _Pragma("unroll") for (int ni = 0; ni < 2; ++ni)                                 \
  _Pragma("unroll") for (int kk = 0; kk < 2; ++kk)                                 \
    DST[ni][kk] = *(const short8*)&lds[BUF][1][NH][wave_n * 32 + ni * 16 + ml]     \
                                                 [((kk * 4 + quad) ^ sw8) * 8];

#define DO_MFMA(MH, NH, AF, BF)                                                    \
  _Pragma("unroll") for (int mi = 0; mi < 4; ++mi)                                 \
  _Pragma("unroll") for (int ni = 0; ni < 2; ++ni) {                               \
    acc[MH][NH][mi][ni] = __builtin_amdgcn_mfma_f32_16x16x32_bf16(                 \
        AF[mi][0], BF[ni][0], acc[MH][NH][mi][ni], 0, 0, 0);                       \
    acc[MH][NH][mi][ni] = __builtin_amdgcn_mfma_f32_16x16x32_bf16(                 \
        AF[mi][1], BF[ni][1], acc[MH][NH][mi][ni], 0, 0, 0);                       \
  }

  f32x4 acc[2][2][4][2] = {};
  short8 aA[4][2], aB[4][2];
  short8 b0[2][2], b1[2][2];

  // prologue: stage tiles 0 and 1 (16 gloads), preload aA/b0 of tile 0
  STG_A(0, 0, 0); STG_B(0, 0, 0);
  STG_B(0, 1, 0);
  STG_A(0, 1, 0);
  STG_A(1, 0, 1); STG_B(1, 0, 1);
  STG_B(1, 1, 1);
  STG_A(1, 1, 1);
  VMCNT(12);
  BAR();
  LOAD_A(0, 0, aA);
  LOAD_B(0, 0, b0);
  VMCNT(8);
  BAR();

  for (int T = 0; T < NKT; ++T) {
    const int buf = T & 1;
    const int ts2 = (T + 2 < NKT) ? T + 2 : NKT - 1;
    // R0
    VMCNT(8);
    LOAD_B(buf, 1, b1);
    BAR();
    __builtin_amdgcn_s_setprio(1);
    DO_MFMA(0, 0, aA, b0);
    __builtin_amdgcn_s_setprio(0);
    BAR();
    // R1
    VMCNT(4);
    STG_A(buf, 0, ts2);
    STG_B(buf, 0, ts2);
    LOAD_A(buf, 1, aB);
    BAR();
    __builtin_amdgcn_s_setprio(1);
    DO_MFMA(0, 1, aA, b1);
    __builtin_amdgcn_s_setprio(0);
    BAR();
    // R2
    STG_B(buf, 1, ts2);
    LOAD_A(buf ^ 1, 0, aA);
    BAR();
    __builtin_amdgcn_s_setprio(1);
    DO_MFMA(1, 0, aB, b0);
    __builtin_amdgcn_s_setprio(0);
    BAR();
    // R3
    VMCNT(8);
    STG_A(buf, 1, ts2);
    LOAD_B(buf ^ 1, 0, b0);
    BAR();
    __builtin_amdgcn_s_setprio(1);
    DO_MFMA(1, 1, aB, b1);
    __builtin_amdgcn_s_setprio(0);
    BAR();
  }
  VMCNT(0);     // drain in-flight tail stages (they write LDS!)
  LGKM0();
  BAR();        // all waves' gloads retired -> LDS reusable as C-staging

  // ---- epilogue: C tile via LDS, full-width stores (no partial-line RFO)
  {
    __hip_bfloat16* sC = &lds[0][0][0][0][0];   // viewed as [256][256] bf16
    // write phase: granule-swizzled (granule ^= (row>>2)&3) -> conflict-free
#pragma unroll
    for (int mh = 0; mh < 2; ++mh)
#pragma unroll
      for (int mi = 0; mi < 4; ++mi)
#pragma unroll
        for (int rr = 0; rr < 4; ++rr) {
          const int row = mh * 128 + wave_m * 64 + mi * 16 + quad * 4 + rr;
          const int gx = ((row >> 2) & 3) << 4;
#pragma unroll
          for (int nh = 0; nh < 2; ++nh)
#pragma unroll
            for (int ni = 0; ni < 2; ++ni) {
              const int col = nh * 128 + wave_n * 32 + ni * 16 + ml;
              sC[row * 256 + (col ^ gx)] = __float2bfloat16(acc[mh][nh][mi][ni][rr]);
            }
        }
    BAR();
    // read-back: wave wid covers rows wid*32..wid*32+31; half-wave per row,
    // 32 lanes x 16B = 512B contiguous per row.
    const int rbase = wid * 32 + (lane >> 5);
    const int col = (lane & 31) * 8;
#pragma unroll
    for (int it = 0; it < 16; ++it) {
      const int row = rbase + it * 2;
      const int scol = ((((col >> 4) ^ ((row >> 2) & 3)) << 4) | (col & 15));
      short8 v = *(const short8*)&sC[row * 256 + scol];
      const int grow = m0 + row;
      if (grow < mvalid)
        *(short8*)(Z + (size_t)grow * (size_t)zcols + (size_t)(n0 + col)) = v;
    }
  }

#undef VMCNT
#undef LGKM0
#undef BAR
#undef STG_A
#undef STG_B
#undef LOAD_A
#undef LOAD_B
#undef DO_MFMA
}

// ---------------------------------------------------------------- aggregation over a slab group of Z
// acc starts as bias (first group) or accf[n] (later groups); accumulates
// sum_r mean_{j in N_r(n)} Z[j][slab r] for relations in this group; last group
// also adds the root slab and finalizes (mode 0: relu->bf16; mode 1: f32 accf==out).
__device__ __forceinline__ void seg_mean_add(const char* cZ, size_t zrb, uint32_t colb,
                                             int beg, int end, int boff, float* acc,
                                             const int* es) {
  float s[12];
#pragma unroll
  for (int i = 0; i < 12; ++i) s[i] = 0.f;
  int e = beg;
  for (; e + 2 <= end; e += 2) {
    const int s0 = es[e], s1 = es[e + 1];
    const char* p0 = cZ + (size_t)s0 * zrb + colb + boff;
    const char* p1 = cZ + (size_t)s1 * zrb + colb + boff;
    const uint2 a0 = *(const uint2*)(p0);
    const uint2 a1 = *(const uint2*)(p0 + 512);
    const uint2 a2 = *(const uint2*)(p0 + 1024);
    const uint2 c0 = *(const uint2*)(p1);
    const uint2 c1 = *(const uint2*)(p1 + 512);
    const uint2 c2 = *(const uint2*)(p1 + 1024);
    s[0]  += bf_lo(a0.x); s[1]  += bf_hi(a0.x);
    s[2]  += bf_lo(a0.y); s[3]  += bf_hi(a0.y);
    s[4]  += bf_lo(a1.x); s[5]  += bf_hi(a1.x);
    s[6]  += bf_lo(a1.y); s[7]  += bf_hi(a1.y);
    s[8]  += bf_lo(a2.x); s[9]  += bf_hi(a2.x);
    s[10] += bf_lo(a2.y); s[11] += bf_hi(a2.y);
    s[0]  += bf_lo(c0.x); s[1]  += bf_hi(c0.x);
    s[2]  += bf_lo(c0.y); s[3]  += bf_hi(c0.y);
    s[4]  += bf_lo(c1.x); s[5]  += bf_hi(c1.x);
    s[6]  += bf_lo(c1.y); s[7]  += bf_hi(c1.y);
    s[8]  += bf_lo(c2.x); s[9]  += bf_hi(c2.x);
    s[10] += bf_lo(c2.y); s[11] += bf_hi(c2.y);
  }
  if (e < end) {
    const int s0 = es[e];
    const char* p0 = cZ + (size_t)s0 * zrb + colb + boff;
    const uint2 a0 = *(const uint2*)(p0);
    const uint2 a1 = *(const uint2*)(p0 + 512);
    const uint2 a2 = *(const uint2*)(p0 + 1024);
    s[0]  += bf_lo(a0.x); s[1]  += bf_hi(a0.x);
    s[2]  += bf_lo(a0.y); s[3]  += bf_hi(a0.y);
    s[4]  += bf_lo(a1.x); s[5]  += bf_hi(a1.x);
    s[6]  += bf_lo(a1.y); s[7]  += bf_hi(a1.y);
    s[8]  += bf_lo(a2.x); s[9]  += bf_hi(a2.x);
    s[10] += bf_lo(a2.y); s[11] += bf_hi(a2.y);
  }
  const float inv = 1.f / (float)(end - beg);
#pragma unroll
  for (int i = 0; i < 12; ++i) acc[i] += s[i] * inv;
}

__global__ __launch_bounds__(256) void aggregate2_kernel(
    const __hip_bfloat16* __restrict__ Z,   // [N_NODES][zcols]
    int zcols,
    const int* __restrict__ soffs, const int* __restrict__ es,
    const float* __restrict__ bias,         // [DIM] f32
    float* __restrict__ accf,               // [N_NODES][DIM] f32 accumulator (== out)
    __hip_bfloat16* __restrict__ outb,      // final bf16 dst (mode 0)
    int g0, int ns, int first, int last, int mode) {
  const int t = threadIdx.x;
  const int lane = t & 63;
  const int wave = t >> 6;
  const int boff = lane * 8;
  const char* cZ = (const char*)Z;
  const size_t zrb = (size_t)zcols * 2;

  int n = (blockIdx.x * 4 + wave) * NPW;
  for (int it = 0; it < NPW; ++it, ++n) {
    if (n >= N_NODES) return;
    float acc[12];
    if (first) {
      const float4 bv0 = *(const float4*)(bias + lane * 4);
      const float4 bv1 = *(const float4*)(bias + 256 + lane * 4);
      const float4 bv2 = *(const float4*)(bias + 512 + lane * 4);
      acc[0] = bv0.x; acc[1] = bv0.y; acc[2] = bv0.z; acc[3] = bv0.w;
      acc[4] = bv1.x; acc[5] = bv1.y; acc[6] = bv1.z; acc[7] = bv1.w;
      acc[8] = bv2.x; acc[9] = bv2.y; acc[10] = bv2.z; acc[11] = bv2.w;
    } else {
      const float* ap = accf + (size_t)n * DIM;
      const float4 v0 = *(const float4*)(ap + lane * 4);
      const float4 v1 = *(const float4*)(ap + 256 + lane * 4);
      const float4 v2 = *(const float4*)(ap + 512 + lane * 4);
      acc[0] = v0.x; acc[1] = v0.y; acc[2] = v0.z; acc[3] = v0.w;
      acc[4] = v1.x; acc[5] = v1.y; acc[6] = v1.z; acc[7] = v1.w;
      acc[8] = v2.x; acc[9] = v2.y; acc[10] = v2.z; acc[11] = v2.w;
    }
    const int rend = imin(g0 + ns, NREL);    // relation slabs in this group
    for (int r = g0; r < rend; ++r) {
      const int beg = soffs[n * NREL + r], end = soffs[n * NREL + r + 1];
      if (beg == end) continue;
      seg_mean_add(cZ, zrb, (uint32_t)(r - g0) * (DIM * 2), beg, end, boff, acc, es);
    }
    if (last) {
      // root slab (index 8) lives in the last group at chunk col (8-g0)*DIM
      const char* zr = cZ + (size_t)n * zrb + (size_t)(NSLAB - 1 - g0) * (DIM * 2);
      const uint2 r0 = *(const uint2*)(zr + boff);
      const uint2 r1 = *(const uint2*)(zr + boff + 512);
      const uint2 r2 = *(const uint2*)(zr + boff + 1024);
      acc[0] += bf_lo(r0.x); acc[1] += bf_hi(r0.x);
      acc[2] += bf_lo(r0.y); acc[3] += bf_hi(r0.y);
      acc[4] += bf_lo(r1.x); acc[5] += bf_hi(r1.x);
      acc[6] += bf_lo(r1.y); acc[7] += bf_hi(r1.y);
      acc[8] += bf_lo(r2.x); acc[9] += bf_hi(r2.x);
      acc[10] += bf_lo(r2.y); acc[11] += bf_hi(r2.y);
    }
    if (!last) {
      float* ap = accf + (size_t)n * DIM;
      float4 v0, v1, v2;
      v0.x = acc[0]; v0.y = acc[1]; v0.z = acc[2]; v0.w = acc[3];
      v1.x = acc[4]; v1.y = acc[5]; v1.z = acc[6]; v1.w = acc[7];
      v2.x = acc[8]; v2.y = acc[9]; v2.z = acc[10]; v2.w = acc[11];
      *(float4*)(ap + lane * 4) = v0;
      *(float4*)(ap + 256 + lane * 4) = v1;
      *(float4*)(ap + 512 + lane * 4) = v2;
    } else if (mode == 0) {
      char* dst = (char*)outb + (size_t)n * (DIM * 2);
      uint2 o0, o1, o2;
      o0.x = pack_bf16x2(fmaxf(acc[0], 0.f), fmaxf(acc[1], 0.f));
      o0.y = pack_bf16x2(fmaxf(acc[2], 0.f), fmaxf(acc[3], 0.f));
      o1.x = pack_bf16x2(fmaxf(acc[4], 0.f), fmaxf(acc[5], 0.f));
      o1.y = pack_bf16x2(fmaxf(acc[6], 0.f), fmaxf(acc[7], 0.f));
      o2.x = pack_bf16x2(fmaxf(acc[8], 0.f), fmaxf(acc[9], 0.f));
      o2.y = pack_bf16x2(fmaxf(acc[10], 0.f), fmaxf(acc[11], 0.f));
      *(uint2*)(dst + boff) = o0;
      *(uint2*)(dst + boff + 512) = o1;
      *(uint2*)(dst + boff + 1024) = o2;
    } else {
      float* ap = accf + (size_t)n * DIM;   // accf == out: final f32 store
      float4 v0, v1, v2;
      v0.x = acc[0]; v0.y = acc[1]; v0.z = acc[2]; v0.w = acc[3];
      v1.x = acc[4]; v1.y = acc[5]; v1.z = acc[6]; v1.w = acc[7];
      v2.x = acc[8]; v2.y = acc[9]; v2.z = acc[10]; v2.w = acc[11];
      *(float4*)(ap + lane * 4) = v0;
      *(float4*)(ap + 256 + lane * 4) = v1;
      *(float4*)(ap + 512 + lane * 4) = v2;
    }
  }
}

// ---------------------------------------------------------------- launch
extern "C" void kernel_launch(void* const* d_in, const int* in_sizes, int n_in,
                              void* d_out, int out_size, void* d_ws, size_t ws_size,
                              hipStream_t stream) {
  const float* x     = (const float*)d_in[0];
  const int*   eidx  = (const int*)d_in[1];     // [2][E]
  const int*   etype = (const int*)d_in[2];
  const float* W1    = (const float*)d_in[3];
  const float* root1 = (const float*)d_in[4];
  const float* b1    = (const float*)d_in[5];
  const float* W2    = (const float*)d_in[6];
  const float* root2 = (const float*)d_in[7];
  const float* b2    = (const float*)d_in[8];
  float* out = (float*)d_out;
  const int* esrc_in = eidx;
  const int* edst_in = eidx + NEDGE;

  char* p = (char*)d_ws;
  auto alloc = [&](size_t bytes) -> char* {
    char* r = p;
    p += (bytes + 255) & ~(size_t)255;
    return r;
  };
  // fixed allocations (~44.5 MB): one weight buffer (re-transposed between
  // layers), CSR scratch, xb (hb aliases xb -- the only hb write is the final
  // layer-1 aggregate, stream-ordered after every gemm read of xb).
  __hip_bfloat16* wt  = (__hip_bfloat16*)alloc((size_t)NSLAB * DIM * KDIM * 2);
  int* segcnt   = (int*)alloc((size_t)NSEG * 4);
  int* soffs    = (int*)alloc((size_t)(NSEG + 1) * 4);
  int* cursor   = (int*)alloc((size_t)NSEG * 4);
  int* partials = (int*)alloc(256 * 4);
  int* es       = (int*)alloc((size_t)NEDGE * 4);
  __hip_bfloat16* xb  = (__hip_bfloat16*)alloc((size_t)N_NODES * DIM * 2);
  __hip_bfloat16* hb  = xb;

  // adaptive slab chunking for Z
  const size_t used = (size_t)(p - (char*)d_ws);
  const size_t remain = (ws_size > used) ? (ws_size - used) : 0;
  const size_t slab_bytes = (size_t)N_NODES * DIM * 2;   // 30.72 MB
  int S = (int)(remain / slab_bytes);
  if (S > NSLAB) S = NSLAB;
  if (S < 1) S = 1;
  __hip_bfloat16* Z = (__hip_bfloat16*)p;

  // --- segment CSR build (edges sorted by (dst, rel)) ---
  const int NB = (NSEG + 1023) / 1024;    // 157
  (void)hipMemsetAsync(segcnt, 0, (size_t)NSEG * 4, stream);
  seg_count_kernel<<<(NEDGE + 255) / 256, 256, 0, stream>>>(edst_in, etype, segcnt, NEDGE);
  block_scan_kernel<<<NB, 1024, 0, stream>>>(segcnt, soffs, partials, NSEG);
  partial_scan_kernel<<<1, 64, 0, stream>>>(partials, NB);
  add_offsets_kernel<<<NB, 1024, 0, stream>>>(soffs, partials, cursor, NSEG);
  seg_scatter_kernel<<<(NEDGE + 255) / 256, 256, 0, stream>>>(esrc_in, edst_in, etype, cursor, es, NEDGE);

  // --- convert x, transpose W1 ---
  cvt_bf16_kernel<<<((N_NODES * DIM / 4) + 255) / 256, 256, 0, stream>>>(
      (const float4*)x, (ushort4*)xb, N_NODES * DIM / 4);
  dim3 tb(32, 8);
  transpose_w2_kernel<<<dim3(DIM / 32, DIM / 32, NSLAB), tb, 0, stream>>>(W1, root1, wt);

  const int agrid = (N_NODES + 4 * NPW - 1) / (4 * NPW);    // 2500

  // --- layer 1: Z = xb @ W1cat^T (slab groups); h = relu(agg(Z) + b1) -> hb ---
  for (int g0 = 0; g0 < NSLAB; g0 += S) {
    const int ns = imin(S, NSLAB - g0);
    const int zc = ns * DIM;
    dim3 gg(zc / 256, (N_NODES + 255) / 256);
    gemm_kernel<<<gg, 512, 0, stream>>>(xb, wt + (size_t)g0 * DIM * KDIM, Z, N_NODES, zc);
    aggregate2_kernel<<<agrid, 256, 0, stream>>>(Z, zc, soffs, es, b1, out, hb,
                                                 g0, ns, g0 == 0, g0 + ns == NSLAB, 0);
  }

  // --- re-transpose weights for layer 2 (after last layer-1 gemm read of wt) ---
  transpose_w2_kernel<<<dim3(DIM / 32, DIM / 32, NSLAB), tb, 0, stream>>>(W2, root2, wt);

  // --- layer 2: Z = hb @ W2cat^T ; out = agg(Z) + b2 (accf == out) ---
  for (int g0 = 0; g0 < NSLAB; g0 += S) {
    const int ns = imin(S, NSLAB - g0);
    const int zc = ns * DIM;
    dim3 gg(zc / 256, (N_NODES + 255) / 256);
    gemm_kernel<<<gg, 512, 0, stream>>>(hb, wt + (size_t)g0 * DIM * KDIM, Z, N_NODES, zc);
    aggregate2_kernel<<<agrid, 256, 0, stream>>>(Z, zc, soffs, es, b2, out, nullptr,
                                                 g0, ns, g0 == 0, g0 + ns == NSLAB, 1);
  }
}